// Round 4
// baseline (362.179 us; speedup 1.0000x reference)
//
#include <hip/hip_runtime.h>

// ---------------------------------------------------------------------------
// MHA without softmax, fully reassociated:
//   out[b] = query[b] @ F[b] + cv[b]
//   F[b]   = 0.125 * WqM[b] @ Wo,  WqM[b] = Wq . blockdiag_h(M[b,h])
//   M[b,h] = Wk_h^T C[b] Wv_h + (Wk_h^T ksum) bv_h^T + bk_h (vsum^T Wv_h) + S bk_h bv_h^T
//   C[b]   = key[b]^T value[b]   (D := value^T key = C^T)
// B=4, S=2048, D=H=1024, heads=16, head_dim=64
// Split-bf16 (hi+lo, 3 MFMAs) GEMMs over pre-tiled images staged by
// global_load_lds; small contractions in exact fp32.
// Round 4: 128x64 tiles (48 KB LDS) -> 512/1024-block grids, 2-4 blocks/CU
// (was 256 blocks = 1/CU, occupancy 10%, MfmaUtil 32%).
// ---------------------------------------------------------------------------

typedef __attribute__((ext_vector_type(8))) short short8;
typedef __attribute__((ext_vector_type(8))) unsigned short ushort8;
typedef __attribute__((ext_vector_type(4))) float f32x4;

__device__ __forceinline__ unsigned short f2bf(float x) {
  unsigned u = __builtin_bit_cast(unsigned, x);
  u += 0x7fffu + ((u >> 16) & 1u);  // RNE
  return (unsigned short)(u >> 16);
}
__device__ __forceinline__ float bf2f(unsigned short b) {
  unsigned u = ((unsigned)b) << 16;
  return __builtin_bit_cast(float, u);
}

__device__ __forceinline__ void gload16(const unsigned short* g, unsigned short* l) {
  __builtin_amdgcn_global_load_lds(
      (const __attribute__((address_space(1))) unsigned int*)g,
      (__attribute__((address_space(3))) unsigned int*)l, 16, 0, 0);
}

// ---------------------------------------------------------------------------
// tileimg: build split-bf16 pre-tiled image of logical matrix R[rows][K].
//   transposed==0: R[r][k] = src[r][k]   (src row-major, 1024 cols)
//   transposed==1: R[r][k] = src[k][r]
// Blob per (rowblk, kt): 8192 ushorts = hi[4][128][8] || lo[4][128][8],
//   hi[ksl][r][j] = bf16(R[rb*128+r][kt*32 + ksl*8 + j]), lo = residue.
// grid: (nRowBlk, NKT, B)
// ---------------------------------------------------------------------------
__global__ __launch_bounds__(256) void tileimg(const float* __restrict__ src,
                                               long long sSrcB, int transposed,
                                               unsigned short* __restrict__ img) {
  const int rb = blockIdx.x, kt = blockIdx.y, b = blockIdx.z;
  const int NRB = gridDim.x, NKT = gridDim.y;
  __shared__ __align__(16) float tile[128][36];
  const int t = threadIdx.x;
  const float* s = src + (size_t)b * sSrcB;
  if (!transposed) {
#pragma unroll
    for (int p = 0; p < 4; ++p) {
      const int idx = p * 1024 + t * 4;
      const int r = idx >> 5, k = idx & 31;
      *(float4*)&tile[r][k] =
          *(const float4*)&s[(size_t)(rb * 128 + r) * 1024 + kt * 32 + k];
    }
  } else {
#pragma unroll
    for (int p = 0; p < 4; ++p) {
      const int idx = p * 1024 + t * 4;
      const int k = idx >> 7, r = idx & 127;
      float4 v = *(const float4*)&s[(size_t)(kt * 32 + k) * 1024 + rb * 128 + r];
      tile[r + 0][k] = v.x;
      tile[r + 1][k] = v.y;
      tile[r + 2][k] = v.z;
      tile[r + 3][k] = v.w;
    }
  }
  __syncthreads();
  unsigned short* blob = img + ((size_t)(b * NRB + rb) * NKT + kt) * 8192;
  const int r = t >> 1, kh = (t & 1) * 16;
  ushort8 hi0, lo0, hi1, lo1;
#pragma unroll
  for (int j = 0; j < 8; ++j) {
    float x = tile[r][kh + j];
    unsigned short h = f2bf(x);
    hi0[j] = h;
    lo0[j] = f2bf(x - bf2f(h));
    float y = tile[r][kh + 8 + j];
    unsigned short g = f2bf(y);
    hi1[j] = g;
    lo1[j] = f2bf(y - bf2f(g));
  }
  const int k0sl = kh >> 3;  // 0 or 2
  *(ushort8*)&blob[k0sl * 1024 + r * 8] = hi0;
  *(ushort8*)&blob[(k0sl + 1) * 1024 + r * 8] = hi1;
  *(ushort8*)&blob[4096 + k0sl * 1024 + r * 8] = lo0;
  *(ushort8*)&blob[4096 + (k0sl + 1) * 1024 + r * 8] = lo1;
}

// ---------------------------------------------------------------------------
// gemm_img: C[m][n] (+bias[n]) = sum_k A[m][k]*BT[n][k], split-bf16 3-MFMA.
// 128x64 tile, BK=32, 4 waves (2x2); LDS double-buffer via global_load_lds.
// B-tile = half of a 128-row blob (by&1 selects the half).
// ---------------------------------------------------------------------------
__global__ __launch_bounds__(256) void gemm_img(
    const unsigned short* __restrict__ Aimg, long long sAb,
    const unsigned short* __restrict__ Bimg, long long sBb,
    const float* __restrict__ bias, long long sBiasB, float* __restrict__ C,
    long long sCb, int NKT) {
  __shared__ __align__(16) unsigned short sA[2][8192];
  __shared__ __align__(16) unsigned short sB[2][4096];
  const int tid = threadIdx.x, w = tid >> 6, l = tid & 63;

  // XCD-chunk swizzle (all grids have total % 8 == 0)
  const int gx = gridDim.x, gy = gridDim.y;
  int flat = blockIdx.x + gx * (blockIdx.y + gy * blockIdx.z);
  const int total = gx * gy * gridDim.z;
  flat = (flat & 7) * (total >> 3) + (flat >> 3);
  const int bx = flat % gx;
  const int rest = flat / gx;
  const int by = rest % gy, bz = rest / gy;
  const int half = by & 1;

  const unsigned short* Ab = Aimg + (size_t)bz * sAb + (size_t)bx * NKT * 8192;
  const unsigned short* Bb = Bimg + (size_t)bz * sBb + (size_t)(by >> 1) * NKT * 8192;

  f32x4 acc[4][2];
#pragma unroll
  for (int m = 0; m < 4; ++m)
#pragma unroll
    for (int n = 0; n < 2; ++n) acc[m][n] = f32x4{0.f, 0.f, 0.f, 0.f};

  const int wr = (w >> 1) * 64, wc = (w & 1) * 32, lr = l & 15, ksl = l >> 4;

  // A blob: 8192 ushorts, 16 chunks of 512; wave w stages chunks 4w..4w+3.
  // B half-tile: 8 chunks of 512 within the blob: c=(hl,s): src hl*4096+s*1024+half*512,
  // dst hl*2048+s*512; wave w stages chunks 2w, 2w+1.
#define STAGE(KT, BUF)                                                      \
  {                                                                         \
    const unsigned short* As_ = Ab + (size_t)(KT)*8192;                     \
    const unsigned short* Bs_ = Bb + (size_t)(KT)*8192;                     \
    _Pragma("unroll") for (int i = 0; i < 4; ++i) {                         \
      const int off = (w * 4 + i) * 512;                                    \
      gload16(As_ + off + l * 8, &sA[BUF][off]);                            \
    }                                                                       \
    _Pragma("unroll") for (int i = 0; i < 2; ++i) {                         \
      const int c = w * 2 + i, hl = c >> 2, s = c & 3;                      \
      gload16(Bs_ + hl * 4096 + s * 1024 + half * 512 + l * 8,              \
              &sB[BUF][hl * 2048 + s * 512]);                               \
    }                                                                       \
  }

  STAGE(0, 0);
  for (int kt = 0; kt < NKT; ++kt) {
    __syncthreads();  // drains vmcnt(0): buf kt&1 ready; prev reads done
    if (kt + 1 < NKT) STAGE(kt + 1, (kt + 1) & 1);
    const unsigned short* sa = sA[kt & 1];
    const unsigned short* sb = sB[kt & 1];
    short8 ah[4], al[4], bh[2], bl[2];
#pragma unroll
    for (int m = 0; m < 4; ++m) {
      const int ro = ksl * 1024 + (wr + m * 16 + lr) * 8;
      ah[m] = *(const short8*)&sa[ro];
      al[m] = *(const short8*)&sa[4096 + ro];
    }
#pragma unroll
    for (int n = 0; n < 2; ++n) {
      const int ro = ksl * 512 + (wc + n * 16 + lr) * 8;
      bh[n] = *(const short8*)&sb[ro];
      bl[n] = *(const short8*)&sb[2048 + ro];
    }
#pragma unroll
    for (int m = 0; m < 4; ++m)
#pragma unroll
      for (int n = 0; n < 2; ++n) {
        acc[m][n] = __builtin_amdgcn_mfma_f32_16x16x32_bf16(ah[m], bh[n], acc[m][n], 0, 0, 0);
        acc[m][n] = __builtin_amdgcn_mfma_f32_16x16x32_bf16(ah[m], bl[n], acc[m][n], 0, 0, 0);
        acc[m][n] = __builtin_amdgcn_mfma_f32_16x16x32_bf16(al[m], bh[n], acc[m][n], 0, 0, 0);
      }
  }
#undef STAGE

  float* Cb = C + (size_t)bz * sCb;
  const size_t m0 = (size_t)bx * 128, n0 = (size_t)by * 64;
#pragma unroll
  for (int n = 0; n < 2; ++n) {
    const size_t col = n0 + wc + n * 16 + lr;
    const float bval = bias ? bias[(size_t)bz * sBiasB + col] : 0.0f;
#pragma unroll
    for (int m = 0; m < 4; ++m) {
      const size_t rb = m0 + wr + m * 16 + ksl * 4;
#pragma unroll
      for (int r = 0; r < 4; ++r)
        Cb[(rb + r) * 1024 + col] = acc[m][n][r] + bval;
    }
  }
}

// ---------------------------------------------------------------------------
// bias-correction inputs: column sums of key/value, u = Wk^T ksum, w = Wv^T vsum
// ---------------------------------------------------------------------------
__global__ __launch_bounds__(256) void colsum2(const float* __restrict__ key,
                                               const float* __restrict__ value,
                                               float* __restrict__ kvpart) {
  const int dseg = blockIdx.x, sc = blockIdx.y, b = blockIdx.z;  // (4,8,4)
  const int d = dseg * 256 + threadIdx.x;
  const float* kp = key + (size_t)b * 2097152 + (size_t)sc * 256 * 1024 + d;
  const float* vp = value + (size_t)b * 2097152 + (size_t)sc * 256 * 1024 + d;
  float sk = 0.f, sv = 0.f;
  for (int s = 0; s < 256; ++s) {
    sk += kp[(size_t)s * 1024];
    sv += vp[(size_t)s * 1024];
  }
  kvpart[((size_t)b * 8 + sc) * 1024 + d] = sk;
  kvpart[32768 + ((size_t)b * 8 + sc) * 1024 + d] = sv;
}

__global__ __launch_bounds__(256) void reduceks(const float* __restrict__ kvpart,
                                                float* __restrict__ ksum,
                                                float* __restrict__ vsum) {
  const int idx = blockIdx.x * 256 + threadIdx.x;  // 4096
  const int b = idx >> 10, d = idx & 1023;
  float sk = 0.f, sv = 0.f;
#pragma unroll
  for (int sc = 0; sc < 8; ++sc) {
    sk += kvpart[((size_t)b * 8 + sc) * 1024 + d];
    sv += kvpart[32768 + ((size_t)b * 8 + sc) * 1024 + d];
  }
  ksum[idx] = sk;
  vsum[idx] = sv;
}

__global__ __launch_bounds__(256) void uvpart_kernel(
    const float* __restrict__ Wk, const float* __restrict__ Wv,
    const float* __restrict__ ksum, const float* __restrict__ vsum,
    float* __restrict__ part) {
  const int iseg = blockIdx.x;                          // 4
  const int dc = blockIdx.y & 7, kv = blockIdx.y >> 3;  // y: 16
  const int b = blockIdx.z;
  const int i = iseg * 256 + threadIdx.x;
  const float* W = kv ? Wv : Wk;
  const float* sv = (kv ? vsum : ksum) + b * 1024 + dc * 128;
  float s = 0.f;
  for (int dd = 0; dd < 128; ++dd)
    s += W[(size_t)(dc * 128 + dd) * 1024 + i] * sv[dd];
  part[(((size_t)kv * 4 + b) * 8 + dc) * 1024 + i] = s;
}

__global__ __launch_bounds__(256) void reduceuv(const float* __restrict__ part,
                                                float* __restrict__ uv) {
  const int idx = blockIdx.x * 256 + threadIdx.x;  // 8192
  const int kb = idx >> 10, i = idx & 1023;
  float s = 0.f;
#pragma unroll
  for (int dc = 0; dc < 8; ++dc) s += part[((size_t)kb * 8 + dc) * 1024 + i];
  uv[idx] = s;
}

// ---------------------------------------------------------------------------
// mstep: Mpart[chunk][bh][r][c] = sum_{e in chunk(256)} T[b][h64+r][e]*Wv[e][h64+c]
// ---------------------------------------------------------------------------
__global__ __launch_bounds__(256) void mstep(const float* __restrict__ T,
                                             const float* __restrict__ Wv,
                                             float* __restrict__ Mpart) {
  const int chunk = blockIdx.x;  // 0..3
  const int bh = blockIdx.y;
  const int b = bh >> 4, h = bh & 15;
  __shared__ float Ts[64][68];
  __shared__ float Ws[64][68];
  const int tid = threadIdx.x;
  const int r0 = tid >> 4, c0 = (tid & 15) * 4;
  float acc[4][4] = {};
  const int e0 = chunk * 256;
  for (int slab = 0; slab < 4; ++slab) {
    __syncthreads();
#pragma unroll
    for (int t = 0; t < 4; ++t) {
      const int task = tid + t * 256;
      const int si = task >> 4, c4 = (task & 15) * 4;
      *(float4*)&Ts[si][c4] = *(const float4*)&T[(size_t)b * 1048576 +
                                                 (size_t)(h * 64 + si) * 1024 +
                                                 e0 + slab * 64 + c4];
      *(float4*)&Ws[si][c4] =
          *(const float4*)&Wv[(size_t)(e0 + slab * 64 + si) * 1024 + h * 64 + c4];
    }
    __syncthreads();
    for (int e = 0; e < 64; ++e) {
      const float4 wv = *(const float4*)&Ws[e][c0];
#pragma unroll
      for (int i = 0; i < 4; ++i) {
        const float tt = Ts[r0 + 16 * i][e];
        acc[i][0] += tt * wv.x;
        acc[i][1] += tt * wv.y;
        acc[i][2] += tt * wv.z;
        acc[i][3] += tt * wv.w;
      }
    }
  }
  float* outp = Mpart + ((size_t)chunk * 64 + bh) * 4096;
#pragma unroll
  for (int i = 0; i < 4; ++i)
    *(float4*)&outp[(r0 + 16 * i) * 64 + c0] = *(float4*)&acc[i][0];
}

// M = sum(Mpart) + rank-1 bias corrections
__global__ __launch_bounds__(256) void reduce4corr(
    const float* __restrict__ Mpart, const float* __restrict__ uv,
    const float* __restrict__ bk, const float* __restrict__ bv,
    float* __restrict__ M) {
  const int idx = blockIdx.x * 256 + threadIdx.x;  // 262144
  const int bh = idx >> 12, b = bh >> 4, h = bh & 15;
  const int rc = idx & 4095;
  const int r = h * 64 + (rc >> 6), c = h * 64 + (rc & 63);
  float s = Mpart[idx] + Mpart[262144 + idx] + Mpart[524288 + idx] +
            Mpart[786432 + idx];
  s += uv[b * 1024 + r] * bv[c] + bk[r] * uv[4096 + b * 1024 + c] +
       2048.0f * bk[r] * bv[c];
  M[idx] = s;
}

// ---------------------------------------------------------------------------
// WqM[b][d][h*64+c] = 0.125 * sum_r Wq[d][h*64+r] * M[b,h][r][c]
// ---------------------------------------------------------------------------
__global__ __launch_bounds__(256) void wqm_kernel(const float* __restrict__ M,
                                                  const float* __restrict__ Wq,
                                                  float* __restrict__ WqM) {
  const int dseg = blockIdx.x, h = blockIdx.y, b = blockIdx.z;
  __shared__ __align__(16) float WqS[128][68];
  __shared__ __align__(16) float Ms[64][68];
  const int t = threadIdx.x;
#pragma unroll
  for (int it = 0; it < 8; ++it) {
    const int task = t + it * 256;
    const int row = task >> 4, c4 = (task & 15) * 4;
    *(float4*)&WqS[row][c4] =
        *(const float4*)&Wq[(size_t)(dseg * 128 + row) * 1024 + h * 64 + c4];
  }
#pragma unroll
  for (int it = 0; it < 4; ++it) {
    const int task = t + it * 256;
    const int row = task >> 4, c4 = (task & 15) * 4;
    *(float4*)&Ms[row][c4] =
        *(const float4*)&M[((size_t)(b * 16 + h)) * 4096 + row * 64 + c4];
  }
  __syncthreads();

  const int c0 = (t & 7) * 8;
  const int d0 = t >> 3;
  float4 a0[4], a1[4];
#pragma unroll
  for (int i = 0; i < 4; ++i) {
    a0[i] = float4{0.f, 0.f, 0.f, 0.f};
    a1[i] = float4{0.f, 0.f, 0.f, 0.f};
  }
  for (int r = 0; r < 64; ++r) {
    const float4 m0 = *(const float4*)&Ms[r][c0];
    const float4 m1 = *(const float4*)&Ms[r][c0 + 4];
#pragma unroll
    for (int i = 0; i < 4; ++i) {
      const float w = WqS[d0 + 32 * i][r];
      a0[i].x += w * m0.x; a0[i].y += w * m0.y; a0[i].z += w * m0.z; a0[i].w += w * m0.w;
      a1[i].x += w * m1.x; a1[i].y += w * m1.y; a1[i].z += w * m1.z; a1[i].w += w * m1.w;
    }
  }
#pragma unroll
  for (int i = 0; i < 4; ++i) {
    const size_t row = (size_t)(dseg * 128 + d0 + 32 * i);
    float* p = WqM + ((size_t)b << 20) + row * 1024 + h * 64 + c0;
    float4 o0 = a0[i], o1 = a1[i];
    o0.x *= 0.125f; o0.y *= 0.125f; o0.z *= 0.125f; o0.w *= 0.125f;
    o1.x *= 0.125f; o1.y *= 0.125f; o1.z *= 0.125f; o1.w *= 0.125f;
    *(float4*)p = o0;
    *(float4*)(p + 4) = o1;
  }
}

// bqM[b][h*64+c] = sum_r bq[h*64+r] * M[b,h][r][c]
__global__ __launch_bounds__(256) void bqm_kernel(const float* __restrict__ M,
                                                  const float* __restrict__ bq,
                                                  float* __restrict__ bqM) {
  const int h = blockIdx.x, b = blockIdx.y;
  __shared__ float part[4][64];
  const int t = threadIdx.x;
  const int c = t & 63, rq = t >> 6;
  const float* Mb = M + ((size_t)(b * 16 + h)) * 4096;
  float s = 0.f;
#pragma unroll
  for (int ri = 0; ri < 16; ++ri) {
    const int r = rq * 16 + ri;
    s += bq[h * 64 + r] * Mb[r * 64 + c];
  }
  part[rq][c] = s;
  __syncthreads();
  if (t < 64) {
    bqM[(size_t)b * 1024 + h * 64 + t] =
        part[0][t] + part[1][t] + part[2][t] + part[3][t];
  }
}

// cv[b][j] = bo[j] + 0.125 * sum_k bqM[b][k] * Wo[k][j]
__global__ __launch_bounds__(256) void cv_kernel(const float* __restrict__ bqM,
                                                 const float* __restrict__ Wo,
                                                 const float* __restrict__ bo,
                                                 float* __restrict__ cv) {
  const int j = blockIdx.x * 256 + threadIdx.x;
  const int b = blockIdx.y;
  const float* q = bqM + (size_t)b * 1024;
  float s = 0.f;
  for (int k = 0; k < 1024; ++k) s += q[k] * Wo[(size_t)k * 1024 + j];
  cv[(size_t)b * 1024 + j] = s * 0.125f + bo[j];
}

extern "C" void kernel_launch(void* const* d_in, const int* in_sizes, int n_in,
                              void* d_out, int out_size, void* d_ws,
                              size_t ws_size, hipStream_t stream) {
  const float* query = (const float*)d_in[0];
  const float* key = (const float*)d_in[1];
  const float* value = (const float*)d_in[2];
  const float* Wq = (const float*)d_in[3];
  const float* bq = (const float*)d_in[4];
  const float* Wk = (const float*)d_in[5];
  const float* bk = (const float*)d_in[6];
  const float* Wv = (const float*)d_in[7];
  const float* bv = (const float*)d_in[8];
  const float* Wo = (const float*)d_in[9];
  const float* bo = (const float*)d_in[10];
  float* out = (float*)d_out;
  float* ws = (float*)d_ws;

  // ---- workspace layout (float offsets; regions reused after producers die)
  unsigned short* KTimg = (unsigned short*)(ws);             // [0, 8388608)
  unsigned short* VTimg = (unsigned short*)(ws + 8388608);   // [8388608, 16777216)
  float* D = ws + 16777216;                                  // [16777216, 20971520)
  unsigned short* Dimg = (unsigned short*)(ws);              // [0, 4194304)  (KTimg dead)
  unsigned short* WkTimg = (unsigned short*)(ws + 4194304);  // [4194304, 5242880)
  unsigned short* WoTimg = (unsigned short*)(ws + 5242880);  // [5242880, 6291456)
  float* T = ws + 6291456;                                   // [6291456, 10485760)
  float* Mpart = ws + 10485760;                              // [10485760, 11534336)
  float* Msum = ws + 11534336;                               // [11534336, 11796480)
  float* WqM = ws + 11804672;                                // [11804672, 15998976)
  unsigned short* WqMimg = (unsigned short*)(ws + 16777216); // reuse D region
  float* FT = ws;                                            // [0, 4194304) (Dimg dead)
  unsigned short* FTimg = (unsigned short*)(ws + 6291456);   // reuse T region
  unsigned short* Qimg = (unsigned short*)(ws + 10485760);   // [10485760, 18874368)
  float* cv = ws + 20971520;
  float* bqM = ws + 20975616;
  float* ksum = ws + 20979712;
  float* vsum = ws + 20983808;
  float* uv = ws + 20987904;
  float* kvpart = ws + 20996096;  // 65536, reused as uvpart

  // ---- phase 1: images of key^T / value^T; bias-correction sums
  tileimg<<<dim3(8, 64, 4), 256, 0, stream>>>(key, 2097152, 1, KTimg);
  tileimg<<<dim3(8, 64, 4), 256, 0, stream>>>(value, 2097152, 1, VTimg);
  colsum2<<<dim3(4, 8, 4), 256, 0, stream>>>(key, value, kvpart);
  reduceks<<<16, 256, 0, stream>>>(kvpart, ksum, vsum);
  uvpart_kernel<<<dim3(4, 16, 4), 256, 0, stream>>>(Wk, Wv, ksum, vsum, kvpart);
  reduceuv<<<32, 256, 0, stream>>>(kvpart, uv);

  // ---- D[b] = value^T key  (= C^T), K=2048
  gemm_img<<<dim3(8, 16, 4), 256, 0, stream>>>(VTimg, 4194304, KTimg, 4194304,
                                               (const float*)nullptr, 0, D,
                                               1048576, 64);

  // ---- T[b] = WkT . D^T  (= Wk^T C)
  tileimg<<<dim3(8, 32, 4), 256, 0, stream>>>(D, 1048576, 0, Dimg);
  tileimg<<<dim3(8, 32, 1), 256, 0, stream>>>(Wk, 0, 1, WkTimg);
  tileimg<<<dim3(8, 32, 1), 256, 0, stream>>>(Wo, 0, 1, WoTimg);
  gemm_img<<<dim3(8, 16, 4), 256, 0, stream>>>(WkTimg, 0, Dimg, 2097152,
                                               (const float*)nullptr, 0, T,
                                               1048576, 32);

  // ---- M[b,h] = T_h . Wv_h + rank-1 bias corrections (fp32 exact)
  mstep<<<dim3(4, 64), 256, 0, stream>>>(T, Wv, Mpart);
  reduce4corr<<<1024, 256, 0, stream>>>(Mpart, uv, bk, bv, Msum);

  // ---- WqM, cv
  wqm_kernel<<<dim3(8, 16, 4), 256, 0, stream>>>(Msum, Wq, WqM);
  bqm_kernel<<<dim3(16, 4), 256, 0, stream>>>(Msum, bq, bqM);
  cv_kernel<<<dim3(4, 4), 256, 0, stream>>>(bqM, Wo, bo, cv);

  // ---- FT[b] = (WqM[b] @ Wo)^T = gemm(A=WoT, BT=WqM)
  tileimg<<<dim3(8, 32, 4), 256, 0, stream>>>(WqM, 1048576, 0, WqMimg);
  gemm_img<<<dim3(8, 16, 4), 256, 0, stream>>>(WoTimg, 0, WqMimg, 2097152,
                                               (const float*)nullptr, 0, FT,
                                               1048576, 32);

  // ---- out[b] = query[b] @ FT[b]^T + cv[b]
  tileimg<<<dim3(8, 32, 4), 256, 0, stream>>>(FT, 1048576, 0, FTimg);
  tileimg<<<dim3(16, 32, 4), 256, 0, stream>>>(query, 2097152, 0, Qimg);
  gemm_img<<<dim3(16, 16, 4), 256, 0, stream>>>(Qimg, 4194304, FTimg, 2097152,
                                                cv, 1024, out, 2097152, 32);
}

// Round 5
// 340.695 us; speedup vs baseline: 1.0631x; 1.0631x over previous
//
#include <hip/hip_runtime.h>

// ---------------------------------------------------------------------------
// MHA without softmax, fully reassociated:
//   out[b] = query[b] @ F[b] + cv[b]
//   F[b]   = 0.125 * WqM[b] @ Wo,  WqM[b] = Wq . blockdiag_h(M[b,h])
//   M[b,h] = Wk_h^T C[b] Wv_h + (Wk_h^T ksum) bv_h^T + bk_h (vsum^T Wv_h) + S bk_h bv_h^T
//   C[b]   = key[b]^T value[b]   (D := value^T key = C^T)
// B=4, S=2048, D=H=1024, heads=16, head_dim=64
// Split-bf16 (hi+lo, 3 MFMAs) GEMMs over pre-tiled images staged by
// global_load_lds.
// Round 5: back to 128x128 tiles (round-3 geometry, best measured) +
// counted-vmcnt double-buffer (T4): raw s_barrier, vmcnt(8) in main loop
// (never 0), STAGE(kt+2) after read-done barrier. Kills the barrier drain.
// ---------------------------------------------------------------------------

typedef __attribute__((ext_vector_type(8))) short short8;
typedef __attribute__((ext_vector_type(8))) unsigned short ushort8;
typedef __attribute__((ext_vector_type(4))) float f32x4;

__device__ __forceinline__ unsigned short f2bf(float x) {
  unsigned u = __builtin_bit_cast(unsigned, x);
  u += 0x7fffu + ((u >> 16) & 1u);  // RNE
  return (unsigned short)(u >> 16);
}
__device__ __forceinline__ float bf2f(unsigned short b) {
  unsigned u = ((unsigned)b) << 16;
  return __builtin_bit_cast(float, u);
}

__device__ __forceinline__ void gload16(const unsigned short* g, unsigned short* l) {
  __builtin_amdgcn_global_load_lds(
      (const __attribute__((address_space(1))) unsigned int*)g,
      (__attribute__((address_space(3))) unsigned int*)l, 16, 0, 0);
}

// ---------------------------------------------------------------------------
// tileimg: build split-bf16 pre-tiled image of logical matrix R[rows][K].
//   transposed==0: R[r][k] = src[r][k]   (src row-major, 1024 cols)
//   transposed==1: R[r][k] = src[k][r]
// Blob per (rowblk, kt): 8192 ushorts = hi[4][128][8] || lo[4][128][8],
//   hi[ksl][r][j] = bf16(R[rb*128+r][kt*32 + ksl*8 + j]), lo = residue.
// grid: (nRowBlk, NKT, B)
// ---------------------------------------------------------------------------
__global__ __launch_bounds__(256) void tileimg(const float* __restrict__ src,
                                               long long sSrcB, int transposed,
                                               unsigned short* __restrict__ img) {
  const int rb = blockIdx.x, kt = blockIdx.y, b = blockIdx.z;
  const int NRB = gridDim.x, NKT = gridDim.y;
  __shared__ __align__(16) float tile[128][36];
  const int t = threadIdx.x;
  const float* s = src + (size_t)b * sSrcB;
  if (!transposed) {
#pragma unroll
    for (int p = 0; p < 4; ++p) {
      const int idx = p * 1024 + t * 4;
      const int r = idx >> 5, k = idx & 31;
      *(float4*)&tile[r][k] =
          *(const float4*)&s[(size_t)(rb * 128 + r) * 1024 + kt * 32 + k];
    }
  } else {
#pragma unroll
    for (int p = 0; p < 4; ++p) {
      const int idx = p * 1024 + t * 4;
      const int k = idx >> 7, r = idx & 127;
      float4 v = *(const float4*)&s[(size_t)(kt * 32 + k) * 1024 + rb * 128 + r];
      tile[r + 0][k] = v.x;
      tile[r + 1][k] = v.y;
      tile[r + 2][k] = v.z;
      tile[r + 3][k] = v.w;
    }
  }
  __syncthreads();
  unsigned short* blob = img + ((size_t)(b * NRB + rb) * NKT + kt) * 8192;
  const int r = t >> 1, kh = (t & 1) * 16;
  ushort8 hi0, lo0, hi1, lo1;
#pragma unroll
  for (int j = 0; j < 8; ++j) {
    float x = tile[r][kh + j];
    unsigned short h = f2bf(x);
    hi0[j] = h;
    lo0[j] = f2bf(x - bf2f(h));
    float y = tile[r][kh + 8 + j];
    unsigned short g = f2bf(y);
    hi1[j] = g;
    lo1[j] = f2bf(y - bf2f(g));
  }
  const int k0sl = kh >> 3;  // 0 or 2
  *(ushort8*)&blob[k0sl * 1024 + r * 8] = hi0;
  *(ushort8*)&blob[(k0sl + 1) * 1024 + r * 8] = hi1;
  *(ushort8*)&blob[4096 + k0sl * 1024 + r * 8] = lo0;
  *(ushort8*)&blob[4096 + (k0sl + 1) * 1024 + r * 8] = lo1;
}

// ---------------------------------------------------------------------------
// gemm_img: C[m][n] (+bias[n]) = sum_k A[m][k]*BT[n][k], split-bf16 3-MFMA.
// 128x128 tile, BK=32, 4 waves (2x2); LDS double-buffer via global_load_lds.
// Counted-vmcnt schedule: next tile's 8 loads stay in flight across the
// barrier (vmcnt(8)); STAGE(kt+2) issued after the read-done barrier.
// ---------------------------------------------------------------------------
__global__ __launch_bounds__(256) void gemm_img(
    const unsigned short* __restrict__ Aimg, long long sAb,
    const unsigned short* __restrict__ Bimg, long long sBb,
    const float* __restrict__ bias, long long sBiasB, float* __restrict__ C,
    long long sCb, int NKT) {
  __shared__ __align__(16) unsigned short sAB[2][16384];
  const int tid = threadIdx.x, w = tid >> 6, l = tid & 63;

  // XCD-chunk swizzle (all grids have total % 8 == 0): each XCD gets a
  // contiguous range of flat tile ids -> B-panel reuse within an XCD L2.
  const int gx = gridDim.x, gy = gridDim.y;
  int flat = blockIdx.x + gx * (blockIdx.y + gy * blockIdx.z);
  const int total = gx * gy * gridDim.z;
  flat = (flat & 7) * (total >> 3) + (flat >> 3);
  const int bx = flat % gx;
  const int rest = flat / gx;
  const int by = rest % gy, bz = rest / gy;

  const unsigned short* Ab = Aimg + (size_t)bz * sAb + (size_t)bx * NKT * 8192;
  const unsigned short* Bb = Bimg + (size_t)bz * sBb + (size_t)by * NKT * 8192;

  f32x4 acc[4][4];
#pragma unroll
  for (int m = 0; m < 4; ++m)
#pragma unroll
    for (int n = 0; n < 4; ++n) acc[m][n] = f32x4{0.f, 0.f, 0.f, 0.f};

  const int wr = (w >> 1) * 64, wc = (w & 1) * 64, lr = l & 15, ksl = l >> 4;
  const int stg = w * 512 + l * 8;

  // 8 load-instructions per thread per k-tile (4 A + 4 B), 16B each.
#define STAGE(KT, BUF)                                                        \
  {                                                                           \
    const unsigned short* As_ = Ab + (size_t)(KT)*8192;                       \
    const unsigned short* Bs_ = Bb + (size_t)(KT)*8192;                       \
    _Pragma("unroll") for (int i = 0; i < 4; ++i)                             \
        gload16(As_ + i * 2048 + stg, &sAB[BUF][i * 2048 + w * 512]);         \
    _Pragma("unroll") for (int i = 0; i < 4; ++i)                             \
        gload16(Bs_ + i * 2048 + stg, &sAB[BUF][8192 + i * 2048 + w * 512]);  \
  }

  STAGE(0, 0);
  STAGE(1, 1);
  for (int kt = 0; kt < NKT; ++kt) {
    // Wait for tile kt's loads only; tile kt+1's 8 loads stay in flight.
    if (kt + 1 < NKT)
      asm volatile("s_waitcnt vmcnt(8)" ::: "memory");
    else
      asm volatile("s_waitcnt vmcnt(0)" ::: "memory");
    __builtin_amdgcn_s_barrier();
    __builtin_amdgcn_sched_barrier(0);

    const unsigned short* sb = sAB[kt & 1];
    short8 ah[4], al[4], bh[4], bl[4];
#pragma unroll
    for (int m = 0; m < 4; ++m) {
      const int ro = ksl * 1024 + (wr + m * 16 + lr) * 8;
      ah[m] = *(const short8*)&sb[ro];
      al[m] = *(const short8*)&sb[4096 + ro];
    }
#pragma unroll
    for (int n = 0; n < 4; ++n) {
      const int ro = ksl * 1024 + (wc + n * 16 + lr) * 8;
      bh[n] = *(const short8*)&sb[8192 + ro];
      bl[n] = *(const short8*)&sb[12288 + ro];
    }
#pragma unroll
    for (int m = 0; m < 4; ++m)
#pragma unroll
      for (int n = 0; n < 4; ++n) {
        acc[m][n] = __builtin_amdgcn_mfma_f32_16x16x32_bf16(ah[m], bh[n], acc[m][n], 0, 0, 0);
        acc[m][n] = __builtin_amdgcn_mfma_f32_16x16x32_bf16(ah[m], bl[n], acc[m][n], 0, 0, 0);
        acc[m][n] = __builtin_amdgcn_mfma_f32_16x16x32_bf16(al[m], bh[n], acc[m][n], 0, 0, 0);
      }

    // All this wave's ds_reads retired; rendezvous, then overwrite buf kt&1.
    asm volatile("s_waitcnt lgkmcnt(0)" ::: "memory");
    __builtin_amdgcn_sched_barrier(0);
    __builtin_amdgcn_s_barrier();
    if (kt + 2 < NKT) STAGE(kt + 2, kt & 1);
  }
#undef STAGE

  float* Cb = C + (size_t)bz * sCb;
  const size_t m0 = (size_t)bx * 128, n0 = (size_t)by * 128;
#pragma unroll
  for (int n = 0; n < 4; ++n) {
    const size_t col = n0 + wc + n * 16 + lr;
    const float bval = bias ? bias[(size_t)bz * sBiasB + col] : 0.0f;
#pragma unroll
    for (int m = 0; m < 4; ++m) {
      const size_t rb = m0 + wr + m * 16 + ksl * 4;
#pragma unroll
      for (int r = 0; r < 4; ++r)
        Cb[(rb + r) * 1024 + col] = acc[m][n][r] + bval;
    }
  }
}

// ---------------------------------------------------------------------------
// bias-correction inputs: column sums of key/value, u = Wk^T ksum, w = Wv^T vsum
// ---------------------------------------------------------------------------
__global__ __launch_bounds__(256) void colsum2(const float* __restrict__ key,
                                               const float* __restrict__ value,
                                               float* __restrict__ kvpart) {
  const int dseg = blockIdx.x, sc = blockIdx.y, b = blockIdx.z;  // (4,8,4)
  const int d = dseg * 256 + threadIdx.x;
  const float* kp = key + (size_t)b * 2097152 + (size_t)sc * 256 * 1024 + d;
  const float* vp = value + (size_t)b * 2097152 + (size_t)sc * 256 * 1024 + d;
  float sk = 0.f, sv = 0.f;
  for (int s = 0; s < 256; ++s) {
    sk += kp[(size_t)s * 1024];
    sv += vp[(size_t)s * 1024];
  }
  kvpart[((size_t)b * 8 + sc) * 1024 + d] = sk;
  kvpart[32768 + ((size_t)b * 8 + sc) * 1024 + d] = sv;
}

__global__ __launch_bounds__(256) void reduceks(const float* __restrict__ kvpart,
                                                float* __restrict__ ksum,
                                                float* __restrict__ vsum) {
  const int idx = blockIdx.x * 256 + threadIdx.x;  // 4096
  const int b = idx >> 10, d = idx & 1023;
  float sk = 0.f, sv = 0.f;
#pragma unroll
  for (int sc = 0; sc < 8; ++sc) {
    sk += kvpart[((size_t)b * 8 + sc) * 1024 + d];
    sv += kvpart[32768 + ((size_t)b * 8 + sc) * 1024 + d];
  }
  ksum[idx] = sk;
  vsum[idx] = sv;
}

__global__ __launch_bounds__(256) void uvpart_kernel(
    const float* __restrict__ Wk, const float* __restrict__ Wv,
    const float* __restrict__ ksum, const float* __restrict__ vsum,
    float* __restrict__ part) {
  const int iseg = blockIdx.x;                          // 4
  const int dc = blockIdx.y & 7, kv = blockIdx.y >> 3;  // y: 16
  const int b = blockIdx.z;
  const int i = iseg * 256 + threadIdx.x;
  const float* W = kv ? Wv : Wk;
  const float* sv = (kv ? vsum : ksum) + b * 1024 + dc * 128;
  float s = 0.f;
  for (int dd = 0; dd < 128; ++dd)
    s += W[(size_t)(dc * 128 + dd) * 1024 + i] * sv[dd];
  part[(((size_t)kv * 4 + b) * 8 + dc) * 1024 + i] = s;
}

__global__ __launch_bounds__(256) void reduceuv(const float* __restrict__ part,
                                                float* __restrict__ uv) {
  const int idx = blockIdx.x * 256 + threadIdx.x;  // 8192
  const int kb = idx >> 10, i = idx & 1023;
  float s = 0.f;
#pragma unroll
  for (int dc = 0; dc < 8; ++dc) s += part[((size_t)kb * 8 + dc) * 1024 + i];
  uv[idx] = s;
}

// ---------------------------------------------------------------------------
// mstep: Mpart[chunk][bh][r][c] = sum_{e in chunk(256)} T[b][h64+r][e]*Wv[e][h64+c]
// ---------------------------------------------------------------------------
__global__ __launch_bounds__(256) void mstep(const float* __restrict__ T,
                                             const float* __restrict__ Wv,
                                             float* __restrict__ Mpart) {
  const int chunk = blockIdx.x;  // 0..3
  const int bh = blockIdx.y;
  const int b = bh >> 4, h = bh & 15;
  __shared__ float Ts[64][68];
  __shared__ float Ws[64][68];
  const int tid = threadIdx.x;
  const int r0 = tid >> 4, c0 = (tid & 15) * 4;
  float acc[4][4] = {};
  const int e0 = chunk * 256;
  for (int slab = 0; slab < 4; ++slab) {
    __syncthreads();
#pragma unroll
    for (int t = 0; t < 4; ++t) {
      const int task = tid + t * 256;
      const int si = task >> 4, c4 = (task & 15) * 4;
      *(float4*)&Ts[si][c4] = *(const float4*)&T[(size_t)b * 1048576 +
                                                 (size_t)(h * 64 + si) * 1024 +
                                                 e0 + slab * 64 + c4];
      *(float4*)&Ws[si][c4] =
          *(const float4*)&Wv[(size_t)(e0 + slab * 64 + si) * 1024 + h * 64 + c4];
    }
    __syncthreads();
    for (int e = 0; e < 64; ++e) {
      const float4 wv = *(const float4*)&Ws[e][c0];
#pragma unroll
      for (int i = 0; i < 4; ++i) {
        const float tt = Ts[r0 + 16 * i][e];
        acc[i][0] += tt * wv.x;
        acc[i][1] += tt * wv.y;
        acc[i][2] += tt * wv.z;
        acc[i][3] += tt * wv.w;
      }
    }
  }
  float* outp = Mpart + ((size_t)chunk * 64 + bh) * 4096;
#pragma unroll
  for (int i = 0; i < 4; ++i)
    *(float4*)&outp[(r0 + 16 * i) * 64 + c0] = *(float4*)&acc[i][0];
}

// M = sum(Mpart) + rank-1 bias corrections
__global__ __launch_bounds__(256) void reduce4corr(
    const float* __restrict__ Mpart, const float* __restrict__ uv,
    const float* __restrict__ bk, const float* __restrict__ bv,
    float* __restrict__ M) {
  const int idx = blockIdx.x * 256 + threadIdx.x;  // 262144
  const int bh = idx >> 12, b = bh >> 4, h = bh & 15;
  const int rc = idx & 4095;
  const int r = h * 64 + (rc >> 6), c = h * 64 + (rc & 63);
  float s = Mpart[idx] + Mpart[262144 + idx] + Mpart[524288 + idx] +
            Mpart[786432 + idx];
  s += uv[b * 1024 + r] * bv[c] + bk[r] * uv[4096 + b * 1024 + c] +
       2048.0f * bk[r] * bv[c];
  M[idx] = s;
}

// ---------------------------------------------------------------------------
// WqM[b][d][h*64+c] = 0.125 * sum_r Wq[d][h*64+r] * M[b,h][r][c]
// ---------------------------------------------------------------------------
__global__ __launch_bounds__(256) void wqm_kernel(const float* __restrict__ M,
                                                  const float* __restrict__ Wq,
                                                  float* __restrict__ WqM) {
  const int dseg = blockIdx.x, h = blockIdx.y, b = blockIdx.z;
  __shared__ __align__(16) float WqS[128][68];
  __shared__ __align__(16) float Ms[64][68];
  const int t = threadIdx.x;
#pragma unroll
  for (int it = 0; it < 8; ++it) {
    const int task = t + it * 256;
    const int row = task >> 4, c4 = (task & 15) * 4;
    *(float4*)&WqS[row][c4] =
        *(const float4*)&Wq[(size_t)(dseg * 128 + row) * 1024 + h * 64 + c4];
  }
#pragma unroll
  for (int it = 0; it < 4; ++it) {
    const int task = t + it * 256;
    const int row = task >> 4, c4 = (task & 15) * 4;
    *(float4*)&Ms[row][c4] =
        *(const float4*)&M[((size_t)(b * 16 + h)) * 4096 + row * 64 + c4];
  }
  __syncthreads();

  const int c0 = (t & 7) * 8;
  const int d0 = t >> 3;
  float4 a0[4], a1[4];
#pragma unroll
  for (int i = 0; i < 4; ++i) {
    a0[i] = float4{0.f, 0.f, 0.f, 0.f};
    a1[i] = float4{0.f, 0.f, 0.f, 0.f};
  }
  for (int r = 0; r < 64; ++r) {
    const float4 m0 = *(const float4*)&Ms[r][c0];
    const float4 m1 = *(const float4*)&Ms[r][c0 + 4];
#pragma unroll
    for (int i = 0; i < 4; ++i) {
      const float w = WqS[d0 + 32 * i][r];
      a0[i].x += w * m0.x; a0[i].y += w * m0.y; a0[i].z += w * m0.z; a0[i].w += w * m0.w;
      a1[i].x += w * m1.x; a1[i].y += w * m1.y; a1[i].z += w * m1.z; a1[i].w += w * m1.w;
    }
  }
#pragma unroll
  for (int i = 0; i < 4; ++i) {
    const size_t row = (size_t)(dseg * 128 + d0 + 32 * i);
    float* p = WqM + ((size_t)b << 20) + row * 1024 + h * 64 + c0;
    float4 o0 = a0[i], o1 = a1[i];
    o0.x *= 0.125f; o0.y *= 0.125f; o0.z *= 0.125f; o0.w *= 0.125f;
    o1.x *= 0.125f; o1.y *= 0.125f; o1.z *= 0.125f; o1.w *= 0.125f;
    *(float4*)p = o0;
    *(float4*)(p + 4) = o1;
  }
}

// bqM[b][h*64+c] = sum_r bq[h*64+r] * M[b,h][r][c]
__global__ __launch_bounds__(256) void bqm_kernel(const float* __restrict__ M,
                                                  const float* __restrict__ bq,
                                                  float* __restrict__ bqM) {
  const int h = blockIdx.x, b = blockIdx.y;
  __shared__ float part[4][64];
  const int t = threadIdx.x;
  const int c = t & 63, rq = t >> 6;
  const float* Mb = M + ((size_t)(b * 16 + h)) * 4096;
  float s = 0.f;
#pragma unroll
  for (int ri = 0; ri < 16; ++ri) {
    const int r = rq * 16 + ri;
    s += bq[h * 64 + r] * Mb[r * 64 + c];
  }
  part[rq][c] = s;
  __syncthreads();
  if (t < 64) {
    bqM[(size_t)b * 1024 + h * 64 + t] =
        part[0][t] + part[1][t] + part[2][t] + part[3][t];
  }
}

// cv[b][j] = bo[j] + 0.125 * sum_k bqM[b][k] * Wo[k][j]
__global__ __launch_bounds__(256) void cv_kernel(const float* __restrict__ bqM,
                                                 const float* __restrict__ Wo,
                                                 const float* __restrict__ bo,
                                                 float* __restrict__ cv) {
  const int j = blockIdx.x * 256 + threadIdx.x;
  const int b = blockIdx.y;
  const float* q = bqM + (size_t)b * 1024;
  float s = 0.f;
  for (int k = 0; k < 1024; ++k) s += q[k] * Wo[(size_t)k * 1024 + j];
  cv[(size_t)b * 1024 + j] = s * 0.125f + bo[j];
}

extern "C" void kernel_launch(void* const* d_in, const int* in_sizes, int n_in,
                              void* d_out, int out_size, void* d_ws,
                              size_t ws_size, hipStream_t stream) {
  const float* query = (const float*)d_in[0];
  const float* key = (const float*)d_in[1];
  const float* value = (const float*)d_in[2];
  const float* Wq = (const float*)d_in[3];
  const float* bq = (const float*)d_in[4];
  const float* Wk = (const float*)d_in[5];
  const float* bk = (const float*)d_in[6];
  const float* Wv = (const float*)d_in[7];
  const float* bv = (const float*)d_in[8];
  const float* Wo = (const float*)d_in[9];
  const float* bo = (const float*)d_in[10];
  float* out = (float*)d_out;
  float* ws = (float*)d_ws;

  // ---- workspace layout (float offsets; regions reused after producers die)
  unsigned short* KTimg = (unsigned short*)(ws);             // [0, 8388608)
  unsigned short* VTimg = (unsigned short*)(ws + 8388608);   // [8388608, 16777216)
  float* D = ws + 16777216;                                  // [16777216, 20971520)
  unsigned short* Dimg = (unsigned short*)(ws);              // [0, 4194304)  (KTimg dead)
  unsigned short* WkTimg = (unsigned short*)(ws + 4194304);  // [4194304, 5242880)
  unsigned short* WoTimg = (unsigned short*)(ws + 5242880);  // [5242880, 6291456)
  float* T = ws + 6291456;                                   // [6291456, 10485760)
  float* Mpart = ws + 10485760;                              // [10485760, 11534336)
  float* Msum = ws + 11534336;                               // [11534336, 11796480)
  float* WqM = ws + 11804672;                                // [11804672, 15998976)
  unsigned short* WqMimg = (unsigned short*)(ws + 16777216); // reuse D region
  float* FT = ws;                                            // [0, 4194304) (Dimg dead)
  unsigned short* FTimg = (unsigned short*)(ws + 6291456);   // reuse T region
  unsigned short* Qimg = (unsigned short*)(ws + 10485760);   // [10485760, 18874368)
  float* cv = ws + 20971520;
  float* bqM = ws + 20975616;
  float* ksum = ws + 20979712;
  float* vsum = ws + 20983808;
  float* uv = ws + 20987904;
  float* kvpart = ws + 20996096;  // 65536, reused as uvpart

  // ---- phase 1: images of key^T / value^T; bias-correction sums
  tileimg<<<dim3(8, 64, 4), 256, 0, stream>>>(key, 2097152, 1, KTimg);
  tileimg<<<dim3(8, 64, 4), 256, 0, stream>>>(value, 2097152, 1, VTimg);
  colsum2<<<dim3(4, 8, 4), 256, 0, stream>>>(key, value, kvpart);
  reduceks<<<16, 256, 0, stream>>>(kvpart, ksum, vsum);
  uvpart_kernel<<<dim3(4, 16, 4), 256, 0, stream>>>(Wk, Wv, ksum, vsum, kvpart);
  reduceuv<<<32, 256, 0, stream>>>(kvpart, uv);

  // ---- D[b] = value^T key  (= C^T), K=2048
  gemm_img<<<dim3(8, 8, 4), 256, 0, stream>>>(VTimg, 4194304, KTimg, 4194304,
                                              (const float*)nullptr, 0, D,
                                              1048576, 64);

  // ---- T[b] = WkT . D^T  (= Wk^T C)
  tileimg<<<dim3(8, 32, 4), 256, 0, stream>>>(D, 1048576, 0, Dimg);
  tileimg<<<dim3(8, 32, 1), 256, 0, stream>>>(Wk, 0, 1, WkTimg);
  tileimg<<<dim3(8, 32, 1), 256, 0, stream>>>(Wo, 0, 1, WoTimg);
  gemm_img<<<dim3(8, 8, 4), 256, 0, stream>>>(WkTimg, 0, Dimg, 2097152,
                                              (const float*)nullptr, 0, T,
                                              1048576, 32);

  // ---- M[b,h] = T_h . Wv_h + rank-1 bias corrections (fp32 exact)
  mstep<<<dim3(4, 64), 256, 0, stream>>>(T, Wv, Mpart);
  reduce4corr<<<1024, 256, 0, stream>>>(Mpart, uv, bk, bv, Msum);

  // ---- WqM, cv
  wqm_kernel<<<dim3(8, 16, 4), 256, 0, stream>>>(Msum, Wq, WqM);
  bqm_kernel<<<dim3(16, 4), 256, 0, stream>>>(Msum, bq, bqM);
  cv_kernel<<<dim3(4, 4), 256, 0, stream>>>(bqM, Wo, bo, cv);

  // ---- FT[b] = (WqM[b] @ Wo)^T = gemm(A=WoT, BT=WqM)
  tileimg<<<dim3(8, 32, 4), 256, 0, stream>>>(WqM, 1048576, 0, WqMimg);
  gemm_img<<<dim3(8, 8, 4), 256, 0, stream>>>(WoTimg, 0, WqMimg, 2097152,
                                              (const float*)nullptr, 0, FT,
                                              1048576, 32);

  // ---- out[b] = query[b] @ FT[b]^T + cv[b]
  tileimg<<<dim3(8, 32, 4), 256, 0, stream>>>(FT, 1048576, 0, FTimg);
  tileimg<<<dim3(16, 32, 4), 256, 0, stream>>>(query, 2097152, 0, Qimg);
  gemm_img<<<dim3(16, 8, 4), 256, 0, stream>>>(Qimg, 4194304, FTimg, 2097152,
                                               cv, 1024, out, 2097152, 32);
}

// Round 7
// 325.988 us; speedup vs baseline: 1.1110x; 1.0451x over previous
//
#include <hip/hip_runtime.h>

// ---------------------------------------------------------------------------
// MHA without softmax, fully reassociated:
//   out[b] = query[b] @ F[b] + cv[b]
//   F[b]   = 0.125 * WqM[b] @ Wo,  WqM[b] = Wq . blockdiag_h(M[b,h])
//   M[b,h] = Wk_h^T C[b] Wv_h + (Wk_h^T ksum) bv_h^T + bk_h (vsum^T Wv_h) + S bk_h bv_h^T
//   C[b]   = key[b]^T value[b]   (D := value^T key = C^T)
// Round 7: round-6 kernels, FIXED workspace layout (round-6 NaN = aliasing:
// VTimg declared at 16MB but written at 32MB; Dpart overwrote live VT image;
// FTimg clobbered cv). ws_size guard picks split-K2-D (96.4MB peak) vs
// nsplit1-D fallback (80.4MB peak).
// ---------------------------------------------------------------------------

typedef __attribute__((ext_vector_type(8))) short short8;
typedef __attribute__((ext_vector_type(8))) unsigned short ushort8;
typedef __attribute__((ext_vector_type(4))) float f32x4;

__device__ __forceinline__ unsigned short f2bf(float x) {
  unsigned u = __builtin_bit_cast(unsigned, x);
  u += 0x7fffu + ((u >> 16) & 1u);  // RNE
  return (unsigned short)(u >> 16);
}
__device__ __forceinline__ float bf2f(unsigned short b) {
  unsigned u = ((unsigned)b) << 16;
  return __builtin_bit_cast(float, u);
}

__device__ __forceinline__ void gload16(const unsigned short* g, unsigned short* l) {
  __builtin_amdgcn_global_load_lds(
      (const __attribute__((address_space(1))) unsigned int*)g,
      (__attribute__((address_space(3))) unsigned int*)l, 16, 0, 0);
}

// ---------------------------------------------------------------------------
// tileimg: split-bf16 pre-tiled image of logical R[rows][K] (1024-col srcs).
//   transposed==0: R[r][k] = src[r][k] ; transposed==1: R[r][k] = src[k][r]
//   bz < splitZ -> src0 (batch bz), else src1 (batch bz-splitZ)
//   nsum==2: element = src[x] + src[x + sumStride]  (fp32 partial reduce)
// Blob per (rowblk, kt): 8192 ushorts = hi[4][128][8] || lo[4][128][8].
// grid: (nRowBlk, NKT, Z)
// ---------------------------------------------------------------------------
__global__ __launch_bounds__(256) void tileimg(
    const float* __restrict__ src0, const float* __restrict__ src1, int splitZ,
    long long sSrcB, int transposed, int nsum, long long sumStride,
    unsigned short* __restrict__ img) {
  const int rb = blockIdx.x, kt = blockIdx.y, bz = blockIdx.z;
  const int NRB = gridDim.x, NKT = gridDim.y;
  __shared__ __align__(16) float tile[128][36];
  const int t = threadIdx.x;
  const float* s;
  int bb;
  if (bz < splitZ) { s = src0; bb = bz; } else { s = src1; bb = bz - splitZ; }
  s += (size_t)bb * sSrcB;
  if (!transposed) {
#pragma unroll
    for (int p = 0; p < 4; ++p) {
      const int idx = p * 1024 + t * 4;
      const int r = idx >> 5, k = idx & 31;
      const size_t off = (size_t)(rb * 128 + r) * 1024 + kt * 32 + k;
      float4 v = *(const float4*)&s[off];
      if (nsum == 2) {
        float4 u = *(const float4*)&s[off + sumStride];
        v.x += u.x; v.y += u.y; v.z += u.z; v.w += u.w;
      }
      *(float4*)&tile[r][k] = v;
    }
  } else {
#pragma unroll
    for (int p = 0; p < 4; ++p) {
      const int idx = p * 1024 + t * 4;
      const int k = idx >> 7, r = idx & 127;
      const size_t off = (size_t)(kt * 32 + k) * 1024 + rb * 128 + r;
      float4 v = *(const float4*)&s[off];
      if (nsum == 2) {
        float4 u = *(const float4*)&s[off + sumStride];
        v.x += u.x; v.y += u.y; v.z += u.z; v.w += u.w;
      }
      tile[r + 0][k] = v.x;
      tile[r + 1][k] = v.y;
      tile[r + 2][k] = v.z;
      tile[r + 3][k] = v.w;
    }
  }
  __syncthreads();
  unsigned short* blob = img + ((size_t)(bz * NRB + rb) * NKT + kt) * 8192;
  const int r = t >> 1, kh = (t & 1) * 16;
  ushort8 hi0, lo0, hi1, lo1;
#pragma unroll
  for (int j = 0; j < 8; ++j) {
    float x = tile[r][kh + j];
    unsigned short h = f2bf(x);
    hi0[j] = h;
    lo0[j] = f2bf(x - bf2f(h));
    float y = tile[r][kh + 8 + j];
    unsigned short g = f2bf(y);
    hi1[j] = g;
    lo1[j] = f2bf(y - bf2f(g));
  }
  const int k0sl = kh >> 3;  // 0 or 2
  *(ushort8*)&blob[k0sl * 1024 + r * 8] = hi0;
  *(ushort8*)&blob[(k0sl + 1) * 1024 + r * 8] = hi1;
  *(ushort8*)&blob[4096 + k0sl * 1024 + r * 8] = lo0;
  *(ushort8*)&blob[4096 + (k0sl + 1) * 1024 + r * 8] = lo1;
}

// ---------------------------------------------------------------------------
// gemm_img: C[m][n] (+bias[n]) = sum_k A[m][k]*BT[n][k], split-bf16 3-MFMA.
// 128x128 tile, BK=32, 4 waves (2x2); LDS double-buffer via global_load_lds.
// Split-K: z = batch*nsplit + split; each split does NKT/nsplit k-tiles and
// writes C + split*sSplit + batch*sCb.
// ---------------------------------------------------------------------------
__global__ __launch_bounds__(256) void gemm_img(
    const unsigned short* __restrict__ Aimg, long long sAb,
    const unsigned short* __restrict__ Bimg, long long sBb,
    const float* __restrict__ bias, long long sBiasB, float* __restrict__ C,
    long long sCb, int NKT, int nsplit, long long sSplit) {
  __shared__ __align__(16) unsigned short sAB[2][16384];
  const int tid = threadIdx.x, w = tid >> 6, l = tid & 63;

  // XCD-chunk swizzle (all grids have total % 8 == 0)
  const int gx = gridDim.x, gy = gridDim.y;
  int flat = blockIdx.x + gx * (blockIdx.y + gy * blockIdx.z);
  const int total = gx * gy * gridDim.z;
  flat = (flat & 7) * (total >> 3) + (flat >> 3);
  const int bx = flat % gx;
  const int rest = flat / gx;
  const int by = rest % gy, bz0 = rest / gy;
  const int batch = bz0 / nsplit, split = bz0 - batch * nsplit;
  const int NKT0 = NKT / nsplit, kt0 = split * NKT0;

  const unsigned short* Ab = Aimg + (size_t)batch * sAb + (size_t)bx * NKT * 8192;
  const unsigned short* Bb = Bimg + (size_t)batch * sBb + (size_t)by * NKT * 8192;

  f32x4 acc[4][4];
#pragma unroll
  for (int m = 0; m < 4; ++m)
#pragma unroll
    for (int n = 0; n < 4; ++n) acc[m][n] = f32x4{0.f, 0.f, 0.f, 0.f};

  const int wr = (w >> 1) * 64, wc = (w & 1) * 64, lr = l & 15, ksl = l >> 4;
  const int stg = w * 512 + l * 8;

#define STAGE(KT, BUF)                                                        \
  {                                                                           \
    const unsigned short* As_ = Ab + (size_t)(KT)*8192;                       \
    const unsigned short* Bs_ = Bb + (size_t)(KT)*8192;                       \
    _Pragma("unroll") for (int i = 0; i < 4; ++i)                             \
        gload16(As_ + i * 2048 + stg, &sAB[BUF][i * 2048 + w * 512]);         \
    _Pragma("unroll") for (int i = 0; i < 4; ++i)                             \
        gload16(Bs_ + i * 2048 + stg, &sAB[BUF][8192 + i * 2048 + w * 512]);  \
  }

  STAGE(kt0, 0);
  for (int kk = 0; kk < NKT0; ++kk) {
    __syncthreads();  // drains vmcnt(0): buf kk&1 ready; prev reads done
    if (kk + 1 < NKT0) STAGE(kt0 + kk + 1, (kk + 1) & 1);
    const unsigned short* sb = sAB[kk & 1];
    short8 ah[4], al[4], bh[4], bl[4];
#pragma unroll
    for (int m = 0; m < 4; ++m) {
      const int ro = ksl * 1024 + (wr + m * 16 + lr) * 8;
      ah[m] = *(const short8*)&sb[ro];
      al[m] = *(const short8*)&sb[4096 + ro];
    }
#pragma unroll
    for (int n = 0; n < 4; ++n) {
      const int ro = ksl * 1024 + (wc + n * 16 + lr) * 8;
      bh[n] = *(const short8*)&sb[8192 + ro];
      bl[n] = *(const short8*)&sb[12288 + ro];
    }
#pragma unroll
    for (int m = 0; m < 4; ++m)
#pragma unroll
      for (int n = 0; n < 4; ++n) {
        acc[m][n] = __builtin_amdgcn_mfma_f32_16x16x32_bf16(ah[m], bh[n], acc[m][n], 0, 0, 0);
        acc[m][n] = __builtin_amdgcn_mfma_f32_16x16x32_bf16(ah[m], bl[n], acc[m][n], 0, 0, 0);
        acc[m][n] = __builtin_amdgcn_mfma_f32_16x16x32_bf16(al[m], bh[n], acc[m][n], 0, 0, 0);
      }
  }
#undef STAGE

  float* Cb = C + (size_t)split * sSplit + (size_t)batch * sCb;
  const size_t m0 = (size_t)bx * 128, n0 = (size_t)by * 128;
#pragma unroll
  for (int n = 0; n < 4; ++n) {
    const size_t col = n0 + wc + n * 16 + lr;
    const float bval = bias ? bias[(size_t)batch * sBiasB + col] : 0.0f;
#pragma unroll
    for (int m = 0; m < 4; ++m) {
      const size_t rb = m0 + wr + m * 16 + ksl * 4;
#pragma unroll
      for (int r = 0; r < 4; ++r)
        Cb[(rb + r) * 1024 + col] = acc[m][n][r] + bval;
    }
  }
}

// ---------------------------------------------------------------------------
// bias-correction inputs: column sums of key/value, u = Wk^T ksum, w = Wv^T vsum
// ---------------------------------------------------------------------------
__global__ __launch_bounds__(256) void colsum2(const float* __restrict__ key,
                                               const float* __restrict__ value,
                                               float* __restrict__ kvpart) {
  const int dseg = blockIdx.x, sc = blockIdx.y, b = blockIdx.z;  // (4,8,4)
  const int d = dseg * 256 + threadIdx.x;
  const float* kp = key + (size_t)b * 2097152 + (size_t)sc * 256 * 1024 + d;
  const float* vp = value + (size_t)b * 2097152 + (size_t)sc * 256 * 1024 + d;
  float sk = 0.f, sv = 0.f;
  for (int s = 0; s < 256; ++s) {
    sk += kp[(size_t)s * 1024];
    sv += vp[(size_t)s * 1024];
  }
  kvpart[((size_t)b * 8 + sc) * 1024 + d] = sk;
  kvpart[32768 + ((size_t)b * 8 + sc) * 1024 + d] = sv;
}

__global__ __launch_bounds__(256) void reduceks(const float* __restrict__ kvpart,
                                                float* __restrict__ ksum,
                                                float* __restrict__ vsum) {
  const int idx = blockIdx.x * 256 + threadIdx.x;  // 4096
  const int b = idx >> 10, d = idx & 1023;
  float sk = 0.f, sv = 0.f;
#pragma unroll
  for (int sc = 0; sc < 8; ++sc) {
    sk += kvpart[((size_t)b * 8 + sc) * 1024 + d];
    sv += kvpart[32768 + ((size_t)b * 8 + sc) * 1024 + d];
  }
  ksum[idx] = sk;
  vsum[idx] = sv;
}

__global__ __launch_bounds__(256) void uvpart_kernel(
    const float* __restrict__ Wk, const float* __restrict__ Wv,
    const float* __restrict__ ksum, const float* __restrict__ vsum,
    float* __restrict__ part) {
  const int iseg = blockIdx.x;                          // 4
  const int dc = blockIdx.y & 7, kv = blockIdx.y >> 3;  // y: 16
  const int b = blockIdx.z;
  const int i = iseg * 256 + threadIdx.x;
  const float* W = kv ? Wv : Wk;
  const float* sv = (kv ? vsum : ksum) + b * 1024 + dc * 128;
  float s = 0.f;
  for (int dd = 0; dd < 128; ++dd)
    s += W[(size_t)(dc * 128 + dd) * 1024 + i] * sv[dd];
  part[(((size_t)kv * 4 + b) * 8 + dc) * 1024 + i] = s;
}

__global__ __launch_bounds__(256) void reduceuv(const float* __restrict__ part,
                                                float* __restrict__ uv) {
  const int idx = blockIdx.x * 256 + threadIdx.x;  // 8192
  const int kb = idx >> 10, i = idx & 1023;
  float s = 0.f;
#pragma unroll
  for (int dc = 0; dc < 8; ++dc) s += part[((size_t)kb * 8 + dc) * 1024 + i];
  uv[idx] = s;
}

// ---------------------------------------------------------------------------
// mstep: Mpart[chunk][bh][r][c] = sum_{e in chunk(256)} T[b][h64+r][e]*Wv[e][h64+c]
// T given as 2 split-K partials: T[x] + T[x + tSplit]
// ---------------------------------------------------------------------------
__global__ __launch_bounds__(256) void mstep(const float* __restrict__ T,
                                             long long tSplit,
                                             const float* __restrict__ Wv,
                                             float* __restrict__ Mpart) {
  const int chunk = blockIdx.x;  // 0..3
  const int bh = blockIdx.y;
  const int b = bh >> 4, h = bh & 15;
  __shared__ float Ts[64][68];
  __shared__ float Ws[64][68];
  const int tid = threadIdx.x;
  const int r0 = tid >> 4, c0 = (tid & 15) * 4;
  float acc[4][4] = {};
  const int e0 = chunk * 256;
  for (int slab = 0; slab < 4; ++slab) {
    __syncthreads();
#pragma unroll
    for (int t = 0; t < 4; ++t) {
      const int task = tid + t * 256;
      const int si = task >> 4, c4 = (task & 15) * 4;
      const size_t toff = (size_t)b * 1048576 + (size_t)(h * 64 + si) * 1024 +
                          e0 + slab * 64 + c4;
      float4 tv = *(const float4*)&T[toff];
      float4 tu = *(const float4*)&T[toff + tSplit];
      tv.x += tu.x; tv.y += tu.y; tv.z += tu.z; tv.w += tu.w;
      *(float4*)&Ts[si][c4] = tv;
      *(float4*)&Ws[si][c4] =
          *(const float4*)&Wv[(size_t)(e0 + slab * 64 + si) * 1024 + h * 64 + c4];
    }
    __syncthreads();
    for (int e = 0; e < 64; ++e) {
      const float4 wv = *(const float4*)&Ws[e][c0];
#pragma unroll
      for (int i = 0; i < 4; ++i) {
        const float tt = Ts[r0 + 16 * i][e];
        acc[i][0] += tt * wv.x;
        acc[i][1] += tt * wv.y;
        acc[i][2] += tt * wv.z;
        acc[i][3] += tt * wv.w;
      }
    }
  }
  float* outp = Mpart + ((size_t)chunk * 64 + bh) * 4096;
#pragma unroll
  for (int i = 0; i < 4; ++i)
    *(float4*)&outp[(r0 + 16 * i) * 64 + c0] = *(float4*)&acc[i][0];
}

// M = sum(Mpart) + rank-1 bias corrections
__global__ __launch_bounds__(256) void reduce4corr(
    const float* __restrict__ Mpart, const float* __restrict__ uv,
    const float* __restrict__ bk, const float* __restrict__ bv,
    float* __restrict__ M) {
  const int idx = blockIdx.x * 256 + threadIdx.x;  // 262144
  const int bh = idx >> 12, b = bh >> 4, h = bh & 15;
  const int rc = idx & 4095;
  const int r = h * 64 + (rc >> 6), c = h * 64 + (rc & 63);
  float s = Mpart[idx] + Mpart[262144 + idx] + Mpart[524288 + idx] +
            Mpart[786432 + idx];
  s += uv[b * 1024 + r] * bv[c] + bk[r] * uv[4096 + b * 1024 + c] +
       2048.0f * bk[r] * bv[c];
  M[idx] = s;
}

// ---------------------------------------------------------------------------
// WqM[b][d][h*64+c] = 0.125 * sum_r Wq[d][h*64+r] * M[b,h][r][c]
// ---------------------------------------------------------------------------
__global__ __launch_bounds__(256) void wqm_kernel(const float* __restrict__ M,
                                                  const float* __restrict__ Wq,
                                                  float* __restrict__ WqM) {
  const int dseg = blockIdx.x, h = blockIdx.y, b = blockIdx.z;
  __shared__ __align__(16) float WqS[128][68];
  __shared__ __align__(16) float Ms[64][68];
  const int t = threadIdx.x;
#pragma unroll
  for (int it = 0; it < 8; ++it) {
    const int task = t + it * 256;
    const int row = task >> 4, c4 = (task & 15) * 4;
    *(float4*)&WqS[row][c4] =
        *(const float4*)&Wq[(size_t)(dseg * 128 + row) * 1024 + h * 64 + c4];
  }
#pragma unroll
  for (int it = 0; it < 4; ++it) {
    const int task = t + it * 256;
    const int row = task >> 4, c4 = (task & 15) * 4;
    *(float4*)&Ms[row][c4] =
        *(const float4*)&M[((size_t)(b * 16 + h)) * 4096 + row * 64 + c4];
  }
  __syncthreads();

  const int c0 = (t & 7) * 8;
  const int d0 = t >> 3;
  float4 a0[4], a1[4];
#pragma unroll
  for (int i = 0; i < 4; ++i) {
    a0[i] = float4{0.f, 0.f, 0.f, 0.f};
    a1[i] = float4{0.f, 0.f, 0.f, 0.f};
  }
  for (int r = 0; r < 64; ++r) {
    const float4 m0 = *(const float4*)&Ms[r][c0];
    const float4 m1 = *(const float4*)&Ms[r][c0 + 4];
#pragma unroll
    for (int i = 0; i < 4; ++i) {
      const float w = WqS[d0 + 32 * i][r];
      a0[i].x += w * m0.x; a0[i].y += w * m0.y; a0[i].z += w * m0.z; a0[i].w += w * m0.w;
      a1[i].x += w * m1.x; a1[i].y += w * m1.y; a1[i].z += w * m1.z; a1[i].w += w * m1.w;
    }
  }
#pragma unroll
  for (int i = 0; i < 4; ++i) {
    const size_t row = (size_t)(dseg * 128 + d0 + 32 * i);
    float* p = WqM + ((size_t)b << 20) + row * 1024 + h * 64 + c0;
    float4 o0 = a0[i], o1 = a1[i];
    o0.x *= 0.125f; o0.y *= 0.125f; o0.z *= 0.125f; o0.w *= 0.125f;
    o1.x *= 0.125f; o1.y *= 0.125f; o1.z *= 0.125f; o1.w *= 0.125f;
    *(float4*)p = o0;
    *(float4*)(p + 4) = o1;
  }
}

// bqM[b][h*64+c] = sum_r bq[h*64+r] * M[b,h][r][c]
__global__ __launch_bounds__(256) void bqm_kernel(const float* __restrict__ M,
                                                  const float* __restrict__ bq,
                                                  float* __restrict__ bqM) {
  const int h = blockIdx.x, b = blockIdx.y;
  __shared__ float part[4][64];
  const int t = threadIdx.x;
  const int c = t & 63, rq = t >> 6;
  const float* Mb = M + ((size_t)(b * 16 + h)) * 4096;
  float s = 0.f;
#pragma unroll
  for (int ri = 0; ri < 16; ++ri) {
    const int r = rq * 16 + ri;
    s += bq[h * 64 + r] * Mb[r * 64 + c];
  }
  part[rq][c] = s;
  __syncthreads();
  if (t < 64) {
    bqM[(size_t)b * 1024 + h * 64 + t] =
        part[0][t] + part[1][t] + part[2][t] + part[3][t];
  }
}

// cv[b][j] = bo[j] + 0.125 * sum_k bqM[b][k] * Wo[k][j]
__global__ __launch_bounds__(256) void cv_kernel(const float* __restrict__ bqM,
                                                 const float* __restrict__ Wo,
                                                 const float* __restrict__ bo,
                                                 float* __restrict__ cv) {
  const int j = blockIdx.x * 256 + threadIdx.x;
  const int b = blockIdx.y;
  const float* q = bqM + (size_t)b * 1024;
  float s = 0.f;
  for (int k = 0; k < 1024; ++k) s += q[k] * Wo[(size_t)k * 1024 + j];
  cv[(size_t)b * 1024 + j] = s * 0.125f + bo[j];
}

extern "C" void kernel_launch(void* const* d_in, const int* in_sizes, int n_in,
                              void* d_out, int out_size, void* d_ws,
                              size_t ws_size, hipStream_t stream) {
  const float* query = (const float*)d_in[0];
  const float* key = (const float*)d_in[1];
  const float* value = (const float*)d_in[2];
  const float* Wq = (const float*)d_in[3];
  const float* bq = (const float*)d_in[4];
  const float* Wk = (const float*)d_in[5];
  const float* bk = (const float*)d_in[6];
  const float* Wv = (const float*)d_in[7];
  const float* bv = (const float*)d_in[8];
  const float* Wo = (const float*)d_in[9];
  const float* bo = (const float*)d_in[10];
  float* out = (float*)d_out;
  float* ws = (float*)d_ws;

  // Big path needs 25165824 + ~89088 floats = 101,019,648 bytes.
  const bool big = ws_size >= (size_t)101019648;
  const int dsplit = big ? 2 : 1;

  // ---- layout (float offsets; MB = bytes/2^20). Timeline-audited. --------
  // [0,64MB)  KT images (z0-3) + VT images (z4-7)       (dead after D gemm)
  //   then: Dimg [0,16) ; WkTimg [16,20) ; WoTimg [20,24) ; Mpart [24,28) ;
  //         Msum [28,29)
  // [32,64MB) Tpart -> FTpart -> Qimg                   (after VT dead)
  // [64,*)    Dpart (big: [64,96) x2 | small: [64,80) x1)
  //   then: WqM [64,80) ; FTimg [64,80)
  // WqMimg: big [80,96) | small [0,16) (Dimg dead after T gemm)
  // smalls:  big @96MB   | small @80MB
  unsigned short* KTimg = (unsigned short*)ws;
  unsigned short* VTimg = (unsigned short*)ws + 16777216;     // 32MB offset
  float* Dpart = ws + 16777216;                               // 64MB
  unsigned short* Dimg = (unsigned short*)ws;                 // 0MB
  unsigned short* WkTimg = (unsigned short*)(ws + 4194304);   // 16MB
  unsigned short* WoTimg = WkTimg + 2097152;                  // 20MB
  float* Mpart = ws + 6291456;                                // 24MB
  float* Msum = ws + 7340032;                                 // 28MB
  float* Tpart = ws + 8388608;                                // 32MB (2x16MB)
  float* WqM = ws + 16777216;                                 // 64MB
  unsigned short* WqMimg = big ? (unsigned short*)(ws + 20971520)  // 80MB
                               : (unsigned short*)ws;              // 0MB
  float* FTpart = ws + 8388608;                               // 32MB (2x16MB)
  unsigned short* FTimg = (unsigned short*)(ws + 16777216);   // 64MB
  unsigned short* Qimg = (unsigned short*)(ws + 8388608);     // 32MB
  float* smalls = ws + (big ? 25165824 : 20971520);           // 96MB | 80MB
  float* kvpart = smalls;          // 65536 fl (reused as uvpart)
  float* ksum = smalls + 65536;    // 4096
  float* vsum = smalls + 69632;    // 4096
  float* uv = smalls + 73728;      // 8192
  float* bqM = smalls + 81920;     // 4096
  float* cv = smalls + 86016;      // 4096

  // ---- t1: images of key^T (z0-3) and value^T (z4-7); bias sums
  tileimg<<<dim3(8, 64, 8), 256, 0, stream>>>(key, value, 4, 2097152, 1, 1, 0,
                                              KTimg);
  colsum2<<<dim3(4, 8, 4), 256, 0, stream>>>(key, value, kvpart);
  reduceks<<<16, 256, 0, stream>>>(kvpart, ksum, vsum);
  uvpart_kernel<<<dim3(4, 16, 4), 256, 0, stream>>>(Wk, Wv, ksum, vsum, kvpart);
  reduceuv<<<32, 256, 0, stream>>>(kvpart, uv);

  // ---- t2: D[b] = value^T key (= C^T), K=2048
  gemm_img<<<dim3(8, 8, 4 * dsplit), 256, 0, stream>>>(
      VTimg, 4194304, KTimg, 4194304, (const float*)nullptr, 0, Dpart, 1048576,
      64, dsplit, 4194304);

  // ---- t3: Dimg = split-bf16 image of sum(Dpart)   (KT region dead)
  tileimg<<<dim3(8, 32, 4), 256, 0, stream>>>(Dpart, nullptr, 4, 1048576, 0,
                                              dsplit, 4194304, Dimg);
  // ---- t4: Wk^T (z0) + Wo^T (z1) images
  tileimg<<<dim3(8, 32, 2), 256, 0, stream>>>(Wk, Wo, 1, 0, 1, 1, 0, WkTimg);

  // ---- t5: T[b] = WkT . D^T (= Wk^T C), split-K x2 -> 512 blocks (VT dead)
  gemm_img<<<dim3(8, 8, 8), 256, 0, stream>>>(WkTimg, 0, Dimg, 2097152,
                                              (const float*)nullptr, 0, Tpart,
                                              1048576, 32, 2, 4194304);

  // ---- t6/t7: M[b,h] = T_h . Wv_h + rank-1 bias corrections (fp32 exact)
  mstep<<<dim3(4, 64), 256, 0, stream>>>(Tpart, 4194304, Wv, Mpart);
  reduce4corr<<<1024, 256, 0, stream>>>(Mpart, uv, bk, bv, Msum);

  // ---- t8/t9: WqM (Dpart dead), cv
  wqm_kernel<<<dim3(8, 16, 4), 256, 0, stream>>>(Msum, Wq, WqM);
  bqm_kernel<<<dim3(16, 4), 256, 0, stream>>>(Msum, bq, bqM);
  cv_kernel<<<dim3(4, 4), 256, 0, stream>>>(bqM, Wo, bo, cv);

  // ---- t10: WqM image (big: 80MB region | small: Dimg region, dead)
  tileimg<<<dim3(8, 32, 4), 256, 0, stream>>>(WqM, nullptr, 4, 1048576, 0, 1,
                                              0, WqMimg);

  // ---- t11: FT[b] = (WqM[b] @ Wo)^T, split-K x2 (Tpart dead)
  gemm_img<<<dim3(8, 8, 8), 256, 0, stream>>>(WoTimg, 0, WqMimg, 2097152,
                                              (const float*)nullptr, 0, FTpart,
                                              1048576, 32, 2, 4194304);

  // ---- t12: FTimg = image of sum(FTpart)  (WqM dead)
  tileimg<<<dim3(8, 32, 4), 256, 0, stream>>>(FTpart, nullptr, 4, 1048576, 0,
                                              2, 4194304, FTimg);

  // ---- t13: query image (FTpart dead)
  tileimg<<<dim3(16, 32, 4), 256, 0, stream>>>(query, nullptr, 4, 2097152, 0,
                                               1, 0, Qimg);

  // ---- t14: out[b] = query[b] @ FT[b]^T + cv[b]  (512 blocks)
  gemm_img<<<dim3(16, 8, 4), 256, 0, stream>>>(Qimg, 4194304, FTimg, 2097152,
                                               cv, 1024, out, 2097152, 32, 1,
                                               0);
}

// Round 8
// 285.464 us; speedup vs baseline: 1.2687x; 1.1420x over previous
//
#include <hip/hip_runtime.h>

// ---------------------------------------------------------------------------
// MHA without softmax, fully reassociated:
//   out[b] = query[b] @ F[b] + cv[b]
//   F[b]   = 0.125 * WqM[b] @ Wo,  WqM[b] = Wq . blockdiag_h(M[b,h])
//   M[b,h] = Wk_h^T C[b] Wv_h + (Wk_h^T ksum) bv_h^T + bk_h (vsum^T Wv_h) + S bk_h bv_h^T
//   C[b]   = key[b]^T value[b]   (D := value^T key = C^T)
// Round 8: GEMMs at structural floor (937 TF-equiv = m97 ceiling). Overhead
// pass: wqm writes split-bf16 image directly (kills WqM fp32 + t10 pass);
// cv split-k (16-block serial matvec -> 48 blocks); colsum2 512 blocks.
// ---------------------------------------------------------------------------

typedef __attribute__((ext_vector_type(8))) short short8;
typedef __attribute__((ext_vector_type(8))) unsigned short ushort8;
typedef __attribute__((ext_vector_type(4))) float f32x4;

__device__ __forceinline__ unsigned short f2bf(float x) {
  unsigned u = __builtin_bit_cast(unsigned, x);
  u += 0x7fffu + ((u >> 16) & 1u);  // RNE
  return (unsigned short)(u >> 16);
}
__device__ __forceinline__ float bf2f(unsigned short b) {
  unsigned u = ((unsigned)b) << 16;
  return __builtin_bit_cast(float, u);
}

__device__ __forceinline__ void gload16(const unsigned short* g, unsigned short* l) {
  __builtin_amdgcn_global_load_lds(
      (const __attribute__((address_space(1))) unsigned int*)g,
      (__attribute__((address_space(3))) unsigned int*)l, 16, 0, 0);
}

// ---------------------------------------------------------------------------
// tileimg: split-bf16 pre-tiled image of logical R[rows][K] (1024-col srcs).
//   transposed==0: R[r][k] = src[r][k] ; transposed==1: R[r][k] = src[k][r]
//   bz < splitZ -> src0 (batch bz), else src1 (batch bz-splitZ)
//   nsum==2: element = src[x] + src[x + sumStride]  (fp32 partial reduce)
// Blob per (rowblk, kt): 8192 ushorts = hi[4][128][8] || lo[4][128][8].
// grid: (nRowBlk, NKT, Z)
// ---------------------------------------------------------------------------
__global__ __launch_bounds__(256) void tileimg(
    const float* __restrict__ src0, const float* __restrict__ src1, int splitZ,
    long long sSrcB, int transposed, int nsum, long long sumStride,
    unsigned short* __restrict__ img) {
  const int rb = blockIdx.x, kt = blockIdx.y, bz = blockIdx.z;
  const int NRB = gridDim.x, NKT = gridDim.y;
  __shared__ __align__(16) float tile[128][36];
  const int t = threadIdx.x;
  const float* s;
  int bb;
  if (bz < splitZ) { s = src0; bb = bz; } else { s = src1; bb = bz - splitZ; }
  s += (size_t)bb * sSrcB;
  if (!transposed) {
#pragma unroll
    for (int p = 0; p < 4; ++p) {
      const int idx = p * 1024 + t * 4;
      const int r = idx >> 5, k = idx & 31;
      const size_t off = (size_t)(rb * 128 + r) * 1024 + kt * 32 + k;
      float4 v = *(const float4*)&s[off];
      if (nsum == 2) {
        float4 u = *(const float4*)&s[off + sumStride];
        v.x += u.x; v.y += u.y; v.z += u.z; v.w += u.w;
      }
      *(float4*)&tile[r][k] = v;
    }
  } else {
#pragma unroll
    for (int p = 0; p < 4; ++p) {
      const int idx = p * 1024 + t * 4;
      const int k = idx >> 7, r = idx & 127;
      const size_t off = (size_t)(kt * 32 + k) * 1024 + rb * 128 + r;
      float4 v = *(const float4*)&s[off];
      if (nsum == 2) {
        float4 u = *(const float4*)&s[off + sumStride];
        v.x += u.x; v.y += u.y; v.z += u.z; v.w += u.w;
      }
      tile[r + 0][k] = v.x;
      tile[r + 1][k] = v.y;
      tile[r + 2][k] = v.z;
      tile[r + 3][k] = v.w;
    }
  }
  __syncthreads();
  unsigned short* blob = img + ((size_t)(bz * NRB + rb) * NKT + kt) * 8192;
  const int r = t >> 1, kh = (t & 1) * 16;
  ushort8 hi0, lo0, hi1, lo1;
#pragma unroll
  for (int j = 0; j < 8; ++j) {
    float x = tile[r][kh + j];
    unsigned short h = f2bf(x);
    hi0[j] = h;
    lo0[j] = f2bf(x - bf2f(h));
    float y = tile[r][kh + 8 + j];
    unsigned short g = f2bf(y);
    hi1[j] = g;
    lo1[j] = f2bf(y - bf2f(g));
  }
  const int k0sl = kh >> 3;  // 0 or 2
  *(ushort8*)&blob[k0sl * 1024 + r * 8] = hi0;
  *(ushort8*)&blob[(k0sl + 1) * 1024 + r * 8] = hi1;
  *(ushort8*)&blob[4096 + k0sl * 1024 + r * 8] = lo0;
  *(ushort8*)&blob[4096 + (k0sl + 1) * 1024 + r * 8] = lo1;
}

// ---------------------------------------------------------------------------
// gemm_img: C[m][n] (+bias[n]) = sum_k A[m][k]*BT[n][k], split-bf16 3-MFMA.
// 128x128 tile, BK=32, 4 waves (2x2); LDS double-buffer via global_load_lds.
// Split-K: z = batch*nsplit + split; each split does NKT/nsplit k-tiles and
// writes C + split*sSplit + batch*sCb.
// ---------------------------------------------------------------------------
__global__ __launch_bounds__(256) void gemm_img(
    const unsigned short* __restrict__ Aimg, long long sAb,
    const unsigned short* __restrict__ Bimg, long long sBb,
    const float* __restrict__ bias, long long sBiasB, float* __restrict__ C,
    long long sCb, int NKT, int nsplit, long long sSplit) {
  __shared__ __align__(16) unsigned short sAB[2][16384];
  const int tid = threadIdx.x, w = tid >> 6, l = tid & 63;

  // XCD-chunk swizzle (all grids have total % 8 == 0)
  const int gx = gridDim.x, gy = gridDim.y;
  int flat = blockIdx.x + gx * (blockIdx.y + gy * blockIdx.z);
  const int total = gx * gy * gridDim.z;
  flat = (flat & 7) * (total >> 3) + (flat >> 3);
  const int bx = flat % gx;
  const int rest = flat / gx;
  const int by = rest % gy, bz0 = rest / gy;
  const int batch = bz0 / nsplit, split = bz0 - batch * nsplit;
  const int NKT0 = NKT / nsplit, kt0 = split * NKT0;

  const unsigned short* Ab = Aimg + (size_t)batch * sAb + (size_t)bx * NKT * 8192;
  const unsigned short* Bb = Bimg + (size_t)batch * sBb + (size_t)by * NKT * 8192;

  f32x4 acc[4][4];
#pragma unroll
  for (int m = 0; m < 4; ++m)
#pragma unroll
    for (int n = 0; n < 4; ++n) acc[m][n] = f32x4{0.f, 0.f, 0.f, 0.f};

  const int wr = (w >> 1) * 64, wc = (w & 1) * 64, lr = l & 15, ksl = l >> 4;
  const int stg = w * 512 + l * 8;

#define STAGE(KT, BUF)                                                        \
  {                                                                           \
    const unsigned short* As_ = Ab + (size_t)(KT)*8192;                       \
    const unsigned short* Bs_ = Bb + (size_t)(KT)*8192;                       \
    _Pragma("unroll") for (int i = 0; i < 4; ++i)                             \
        gload16(As_ + i * 2048 + stg, &sAB[BUF][i * 2048 + w * 512]);         \
    _Pragma("unroll") for (int i = 0; i < 4; ++i)                             \
        gload16(Bs_ + i * 2048 + stg, &sAB[BUF][8192 + i * 2048 + w * 512]);  \
  }

  STAGE(kt0, 0);
  for (int kk = 0; kk < NKT0; ++kk) {
    __syncthreads();  // drains vmcnt(0): buf kk&1 ready; prev reads done
    if (kk + 1 < NKT0) STAGE(kt0 + kk + 1, (kk + 1) & 1);
    const unsigned short* sb = sAB[kk & 1];
    short8 ah[4], al[4], bh[4], bl[4];
#pragma unroll
    for (int m = 0; m < 4; ++m) {
      const int ro = ksl * 1024 + (wr + m * 16 + lr) * 8;
      ah[m] = *(const short8*)&sb[ro];
      al[m] = *(const short8*)&sb[4096 + ro];
    }
#pragma unroll
    for (int n = 0; n < 4; ++n) {
      const int ro = ksl * 1024 + (wc + n * 16 + lr) * 8;
      bh[n] = *(const short8*)&sb[8192 + ro];
      bl[n] = *(const short8*)&sb[12288 + ro];
    }
#pragma unroll
    for (int m = 0; m < 4; ++m)
#pragma unroll
      for (int n = 0; n < 4; ++n) {
        acc[m][n] = __builtin_amdgcn_mfma_f32_16x16x32_bf16(ah[m], bh[n], acc[m][n], 0, 0, 0);
        acc[m][n] = __builtin_amdgcn_mfma_f32_16x16x32_bf16(ah[m], bl[n], acc[m][n], 0, 0, 0);
        acc[m][n] = __builtin_amdgcn_mfma_f32_16x16x32_bf16(al[m], bh[n], acc[m][n], 0, 0, 0);
      }
  }
#undef STAGE

  float* Cb = C + (size_t)split * sSplit + (size_t)batch * sCb;
  const size_t m0 = (size_t)bx * 128, n0 = (size_t)by * 128;
#pragma unroll
  for (int n = 0; n < 4; ++n) {
    const size_t col = n0 + wc + n * 16 + lr;
    const float bval = bias ? bias[(size_t)batch * sBiasB + col] : 0.0f;
#pragma unroll
    for (int m = 0; m < 4; ++m) {
      const size_t rb = m0 + wr + m * 16 + ksl * 4;
#pragma unroll
      for (int r = 0; r < 4; ++r)
        Cb[(rb + r) * 1024 + col] = acc[m][n][r] + bval;
    }
  }
}

// ---------------------------------------------------------------------------
// bias-correction inputs: column sums of key/value, u = Wk^T ksum, w = Wv^T vsum
// grid (4,32,4): dseg x s-chunk(64) x batch -> 512 blocks (HBM-floor)
// ---------------------------------------------------------------------------
__global__ __launch_bounds__(256) void colsum2(const float* __restrict__ key,
                                               const float* __restrict__ value,
                                               float* __restrict__ kvpart) {
  const int dseg = blockIdx.x, sc = blockIdx.y, b = blockIdx.z;
  const int d = dseg * 256 + threadIdx.x;
  const float* kp = key + (size_t)b * 2097152 + (size_t)sc * 64 * 1024 + d;
  const float* vp = value + (size_t)b * 2097152 + (size_t)sc * 64 * 1024 + d;
  float sk = 0.f, sv = 0.f;
  for (int s = 0; s < 64; ++s) {
    sk += kp[(size_t)s * 1024];
    sv += vp[(size_t)s * 1024];
  }
  kvpart[((size_t)b * 32 + sc) * 1024 + d] = sk;
  kvpart[131072 + ((size_t)b * 32 + sc) * 1024 + d] = sv;
}

__global__ __launch_bounds__(256) void reduceks(const float* __restrict__ kvpart,
                                                float* __restrict__ ksum,
                                                float* __restrict__ vsum) {
  const int idx = blockIdx.x * 256 + threadIdx.x;  // 4096
  const int b = idx >> 10, d = idx & 1023;
  float sk = 0.f, sv = 0.f;
#pragma unroll
  for (int sc = 0; sc < 32; ++sc) {
    sk += kvpart[((size_t)b * 32 + sc) * 1024 + d];
    sv += kvpart[131072 + ((size_t)b * 32 + sc) * 1024 + d];
  }
  ksum[idx] = sk;
  vsum[idx] = sv;
}

__global__ __launch_bounds__(256) void uvpart_kernel(
    const float* __restrict__ Wk, const float* __restrict__ Wv,
    const float* __restrict__ ksum, const float* __restrict__ vsum,
    float* __restrict__ part) {
  const int iseg = blockIdx.x;                          // 4
  const int dc = blockIdx.y & 7, kv = blockIdx.y >> 3;  // y: 16
  const int b = blockIdx.z;
  const int i = iseg * 256 + threadIdx.x;
  const float* W = kv ? Wv : Wk;
  const float* sv = (kv ? vsum : ksum) + b * 1024 + dc * 128;
  float s = 0.f;
  for (int dd = 0; dd < 128; ++dd)
    s += W[(size_t)(dc * 128 + dd) * 1024 + i] * sv[dd];
  part[(((size_t)kv * 4 + b) * 8 + dc) * 1024 + i] = s;
}

__global__ __launch_bounds__(256) void reduceuv(const float* __restrict__ part,
                                                float* __restrict__ uv) {
  const int idx = blockIdx.x * 256 + threadIdx.x;  // 8192
  const int kb = idx >> 10, i = idx & 1023;
  float s = 0.f;
#pragma unroll
  for (int dc = 0; dc < 8; ++dc) s += part[((size_t)kb * 8 + dc) * 1024 + i];
  uv[idx] = s;
}

// ---------------------------------------------------------------------------
// mstep: Mpart[chunk][bh][r][c] = sum_{e in chunk(256)} T[b][h64+r][e]*Wv[e][h64+c]
// T given as 2 split-K partials: T[x] + T[x + tSplit]
// ---------------------------------------------------------------------------
__global__ __launch_bounds__(256) void mstep(const float* __restrict__ T,
                                             long long tSplit,
                                             const float* __restrict__ Wv,
                                             float* __restrict__ Mpart) {
  const int chunk = blockIdx.x;  // 0..3
  const int bh = blockIdx.y;
  const int b = bh >> 4, h = bh & 15;
  __shared__ float Ts[64][68];
  __shared__ float Ws[64][68];
  const int tid = threadIdx.x;
  const int r0 = tid >> 4, c0 = (tid & 15) * 4;
  float acc[4][4] = {};
  const int e0 = chunk * 256;
  for (int slab = 0; slab < 4; ++slab) {
    __syncthreads();
#pragma unroll
    for (int t = 0; t < 4; ++t) {
      const int task = tid + t * 256;
      const int si = task >> 4, c4 = (task & 15) * 4;
      const size_t toff = (size_t)b * 1048576 + (size_t)(h * 64 + si) * 1024 +
                          e0 + slab * 64 + c4;
      float4 tv = *(const float4*)&T[toff];
      float4 tu = *(const float4*)&T[toff + tSplit];
      tv.x += tu.x; tv.y += tu.y; tv.z += tu.z; tv.w += tu.w;
      *(float4*)&Ts[si][c4] = tv;
      *(float4*)&Ws[si][c4] =
          *(const float4*)&Wv[(size_t)(e0 + slab * 64 + si) * 1024 + h * 64 + c4];
    }
    __syncthreads();
    for (int e = 0; e < 64; ++e) {
      const float4 wv = *(const float4*)&Ws[e][c0];
#pragma unroll
      for (int i = 0; i < 4; ++i) {
        const float tt = Ts[r0 + 16 * i][e];
        acc[i][0] += tt * wv.x;
        acc[i][1] += tt * wv.y;
        acc[i][2] += tt * wv.z;
        acc[i][3] += tt * wv.w;
      }
    }
  }
  float* outp = Mpart + ((size_t)chunk * 64 + bh) * 4096;
#pragma unroll
  for (int i = 0; i < 4; ++i)
    *(float4*)&outp[(r0 + 16 * i) * 64 + c0] = *(float4*)&acc[i][0];
}

// M = sum(Mpart) + rank-1 bias corrections
__global__ __launch_bounds__(256) void reduce4corr(
    const float* __restrict__ Mpart, const float* __restrict__ uv,
    const float* __restrict__ bk, const float* __restrict__ bv,
    float* __restrict__ M) {
  const int idx = blockIdx.x * 256 + threadIdx.x;  // 262144
  const int bh = idx >> 12, b = bh >> 4, h = bh & 15;
  const int rc = idx & 4095;
  const int r = h * 64 + (rc >> 6), c = h * 64 + (rc & 63);
  float s = Mpart[idx] + Mpart[262144 + idx] + Mpart[524288 + idx] +
            Mpart[786432 + idx];
  s += uv[b * 1024 + r] * bv[c] + bk[r] * uv[4096 + b * 1024 + c] +
       2048.0f * bk[r] * bv[c];
  M[idx] = s;
}

// ---------------------------------------------------------------------------
// wqm_kernel: WqM[b][d][h*64+c] = 0.125 * sum_r Wq[d][h*64+r] * M[b,h][r][c],
// written DIRECTLY as split-bf16 image (blob rb=dseg, kt=h*2+(c0>=32),
// ksl=(c0/8)&3, r=d%128) -- no fp32 WqM, no separate tileimg pass.
// ---------------------------------------------------------------------------
__global__ __launch_bounds__(256) void wqm_kernel(const float* __restrict__ M,
                                                  const float* __restrict__ Wq,
                                                  unsigned short* __restrict__ img) {
  const int dseg = blockIdx.x, h = blockIdx.y, b = blockIdx.z;
  __shared__ __align__(16) float WqS[128][68];
  __shared__ __align__(16) float Ms[64][68];
  const int t = threadIdx.x;
#pragma unroll
  for (int it = 0; it < 8; ++it) {
    const int task = t + it * 256;
    const int row = task >> 4, c4 = (task & 15) * 4;
    *(float4*)&WqS[row][c4] =
        *(const float4*)&Wq[(size_t)(dseg * 128 + row) * 1024 + h * 64 + c4];
  }
#pragma unroll
  for (int it = 0; it < 4; ++it) {
    const int task = t + it * 256;
    const int row = task >> 4, c4 = (task & 15) * 4;
    *(float4*)&Ms[row][c4] =
        *(const float4*)&M[((size_t)(b * 16 + h)) * 4096 + row * 64 + c4];
  }
  __syncthreads();

  const int c0 = (t & 7) * 8;
  const int d0 = t >> 3;
  float4 a0[4], a1[4];
#pragma unroll
  for (int i = 0; i < 4; ++i) {
    a0[i] = float4{0.f, 0.f, 0.f, 0.f};
    a1[i] = float4{0.f, 0.f, 0.f, 0.f};
  }
  for (int r = 0; r < 64; ++r) {
    const float4 m0 = *(const float4*)&Ms[r][c0];
    const float4 m1 = *(const float4*)&Ms[r][c0 + 4];
#pragma unroll
    for (int i = 0; i < 4; ++i) {
      const float w = WqS[d0 + 32 * i][r];
      a0[i].x += w * m0.x; a0[i].y += w * m0.y; a0[i].z += w * m0.z; a0[i].w += w * m0.w;
      a1[i].x += w * m1.x; a1[i].y += w * m1.y; a1[i].z += w * m1.z; a1[i].w += w * m1.w;
    }
  }
  const int kt = h * 2 + (c0 >> 5);
  const int ksl = (c0 >> 3) & 3;
  unsigned short* blob = img + ((size_t)((b * 8 + dseg) * 32 + kt)) * 8192;
#pragma unroll
  for (int i = 0; i < 4; ++i) {
    const int r = d0 + 32 * i;
    float v[8] = {a0[i].x * 0.125f, a0[i].y * 0.125f, a0[i].z * 0.125f,
                  a0[i].w * 0.125f, a1[i].x * 0.125f, a1[i].y * 0.125f,
                  a1[i].z * 0.125f, a1[i].w * 0.125f};
    ushort8 hi, lo;
#pragma unroll
    for (int j = 0; j < 8; ++j) {
      unsigned short hh = f2bf(v[j]);
      hi[j] = hh;
      lo[j] = f2bf(v[j] - bf2f(hh));
    }
    *(ushort8*)&blob[ksl * 1024 + r * 8] = hi;
    *(ushort8*)&blob[4096 + ksl * 1024 + r * 8] = lo;
  }
}

// bqM[b][h*64+c] = sum_r bq[h*64+r] * M[b,h][r][c]
__global__ __launch_bounds__(256) void bqm_kernel(const float* __restrict__ M,
                                                  const float* __restrict__ bq,
                                                  float* __restrict__ bqM) {
  const int h = blockIdx.x, b = blockIdx.y;
  __shared__ float part[4][64];
  const int t = threadIdx.x;
  const int c = t & 63, rq = t >> 6;
  const float* Mb = M + ((size_t)(b * 16 + h)) * 4096;
  float s = 0.f;
#pragma unroll
  for (int ri = 0; ri < 16; ++ri) {
    const int r = rq * 16 + ri;
    s += bq[h * 64 + r] * Mb[r * 64 + c];
  }
  part[rq][c] = s;
  __syncthreads();
  if (t < 64) {
    bqM[(size_t)b * 1024 + h * 64 + t] =
        part[0][t] + part[1][t] + part[2][t] + part[3][t];
  }
}

// cvpart[(b*8+ks)*1024+j] = sum_{k in ks-chunk(128)} bqM[b][k]*Wo[k][j]
// grid (4 jseg, 8 ks): Wo read once; all 4 batches per thread.
__global__ __launch_bounds__(256) void cvpart_kernel(
    const float* __restrict__ bqM, const float* __restrict__ Wo,
    float* __restrict__ cvpart) {
  const int jseg = blockIdx.x, ks = blockIdx.y;
  const int j = jseg * 256 + threadIdx.x;
  float s0 = 0.f, s1 = 0.f, s2 = 0.f, s3 = 0.f;
  for (int k = 0; k < 128; ++k) {
    const float wv = Wo[(size_t)(ks * 128 + k) * 1024 + j];
    s0 += bqM[ks * 128 + k] * wv;
    s1 += bqM[1024 + ks * 128 + k] * wv;
    s2 += bqM[2048 + ks * 128 + k] * wv;
    s3 += bqM[3072 + ks * 128 + k] * wv;
  }
  cvpart[((size_t)0 * 8 + ks) * 1024 + j] = s0;
  cvpart[((size_t)1 * 8 + ks) * 1024 + j] = s1;
  cvpart[((size_t)2 * 8 + ks) * 1024 + j] = s2;
  cvpart[((size_t)3 * 8 + ks) * 1024 + j] = s3;
}

// cv[b][j] = bo[j] + 0.125 * sum_ks cvpart[(b*8+ks)*1024+j]
__global__ __launch_bounds__(256) void cvred(const float* __restrict__ cvpart,
                                             const float* __restrict__ bo,
                                             float* __restrict__ cv) {
  const int idx = blockIdx.x * 256 + threadIdx.x;  // 4096
  const int b = idx >> 10, j = idx & 1023;
  float s = 0.f;
#pragma unroll
  for (int ks = 0; ks < 8; ++ks) s += cvpart[((size_t)b * 8 + ks) * 1024 + j];
  cv[idx] = s * 0.125f + bo[j];
}

extern "C" void kernel_launch(void* const* d_in, const int* in_sizes, int n_in,
                              void* d_out, int out_size, void* d_ws,
                              size_t ws_size, hipStream_t stream) {
  const float* query = (const float*)d_in[0];
  const float* key = (const float*)d_in[1];
  const float* value = (const float*)d_in[2];
  const float* Wq = (const float*)d_in[3];
  const float* bq = (const float*)d_in[4];
  const float* Wk = (const float*)d_in[5];
  const float* bk = (const float*)d_in[6];
  const float* Wv = (const float*)d_in[7];
  const float* bv = (const float*)d_in[8];
  const float* Wo = (const float*)d_in[9];
  const float* bo = (const float*)d_in[10];
  float* out = (float*)d_out;
  float* ws = (float*)d_ws;

  // Big path peak: 96MB regions + smalls (57344 fl) = 100,892,672 B.
  const bool big = ws_size >= (size_t)101019648;
  const int dsplit = big ? 2 : 1;

  // ---- layout (float offsets). Timeline-audited.
  // [0,64MB)  KT(z0-3)+VT(z4-7) images  -> after t5: WqMimg [0,16) ;
  //           WkTimg [16,20) ; WoTimg [20,24) ; Mpart [24,28) ; Msum [28,29)
  // [32,64MB) Tpart -> FTpart -> Qimg
  // [64,*)    kvpart/uvpart (early) -> Dpart (big [64,96) | small [64,80))
  //           -> FTimg [64,80)
  // smalls:   big @96MB | small @80MB
  unsigned short* KTimg = (unsigned short*)ws;
  unsigned short* VTimg = (unsigned short*)ws + 16777216;     // 32MB
  float* kvpart = ws + 16777216;                              // 64MB (early)
  float* Dpart = ws + 16777216;                               // 64MB
  unsigned short* Dimg = (unsigned short*)ws;                 // 0MB
  unsigned short* WkTimg = (unsigned short*)(ws + 4194304);   // 16MB
  unsigned short* WoTimg = WkTimg + 2097152;                  // 20MB
  float* Mpart = ws + 6291456;                                // 24MB
  float* Msum = ws + 7340032;                                 // 28MB
  float* Tpart = ws + 8388608;                                // 32MB (2x16MB)
  unsigned short* WqMimg = (unsigned short*)ws;               // 0MB (Dimg dead)
  float* FTpart = ws + 8388608;                               // 32MB (2x16MB)
  unsigned short* FTimg = (unsigned short*)(ws + 16777216);   // 64MB
  unsigned short* Qimg = (unsigned short*)(ws + 8388608);     // 32MB
  float* smalls = ws + (big ? 25165824 : 20971520);           // 96MB | 80MB
  float* ksum = smalls;            // 4096
  float* vsum = smalls + 4096;     // 4096
  float* uv = smalls + 8192;       // 8192
  float* bqM = smalls + 16384;     // 4096
  float* cvpartb = smalls + 20480; // 32768
  float* cv = smalls + 53248;      // 4096

  // ---- t1: images of key^T (z0-3) and value^T (z4-7); bias sums
  tileimg<<<dim3(8, 64, 8), 256, 0, stream>>>(key, value, 4, 2097152, 1, 1, 0,
                                              KTimg);
  colsum2<<<dim3(4, 32, 4), 256, 0, stream>>>(key, value, kvpart);
  reduceks<<<16, 256, 0, stream>>>(kvpart, ksum, vsum);
  uvpart_kernel<<<dim3(4, 16, 4), 256, 0, stream>>>(Wk, Wv, ksum, vsum, kvpart);
  reduceuv<<<32, 256, 0, stream>>>(kvpart, uv);

  // ---- t2: D[b] = value^T key (= C^T), K=2048
  gemm_img<<<dim3(8, 8, 4 * dsplit), 256, 0, stream>>>(
      VTimg, 4194304, KTimg, 4194304, (const float*)nullptr, 0, Dpart, 1048576,
      64, dsplit, 4194304);

  // ---- t3: Dimg = split-bf16 image of sum(Dpart)   (KT region dead)
  tileimg<<<dim3(8, 32, 4), 256, 0, stream>>>(Dpart, nullptr, 4, 1048576, 0,
                                              dsplit, 4194304, Dimg);
  // ---- t4: Wk^T (z0) + Wo^T (z1) images
  tileimg<<<dim3(8, 32, 2), 256, 0, stream>>>(Wk, Wo, 1, 0, 1, 1, 0, WkTimg);

  // ---- t5: T[b] = WkT . D^T (= Wk^T C), split-K x2 -> 512 blocks (VT dead)
  gemm_img<<<dim3(8, 8, 8), 256, 0, stream>>>(WkTimg, 0, Dimg, 2097152,
                                              (const float*)nullptr, 0, Tpart,
                                              1048576, 32, 2, 4194304);

  // ---- t6/t7: M[b,h] = T_h . Wv_h + rank-1 bias corrections (fp32 exact)
  mstep<<<dim3(4, 64), 256, 0, stream>>>(Tpart, 4194304, Wv, Mpart);
  reduce4corr<<<1024, 256, 0, stream>>>(Mpart, uv, bk, bv, Msum);

  // ---- t8: WqM image directly (Dimg region dead after t5)
  wqm_kernel<<<dim3(8, 16, 4), 256, 0, stream>>>(Msum, Wq, WqMimg);
  bqm_kernel<<<dim3(16, 4), 256, 0, stream>>>(Msum, bq, bqM);
  cvpart_kernel<<<dim3(4, 8), 256, 0, stream>>>(bqM, Wo, cvpartb);
  cvred<<<16, 256, 0, stream>>>(cvpartb, bo, cv);

  // ---- t11: FT[b] = (WqM[b] @ Wo)^T, split-K x2 (Tpart dead)
  gemm_img<<<dim3(8, 8, 8), 256, 0, stream>>>(WoTimg, 0, WqMimg, 2097152,
                                              (const float*)nullptr, 0, FTpart,
                                              1048576, 32, 2, 4194304);

  // ---- t12: FTimg = image of sum(FTpart)
  tileimg<<<dim3(8, 32, 4), 256, 0, stream>>>(FTpart, nullptr, 4, 1048576, 0,
                                              2, 4194304, FTimg);

  // ---- t13: query image (FTpart dead)
  tileimg<<<dim3(16, 32, 4), 256, 0, stream>>>(query, nullptr, 4, 2097152, 0,
                                               1, 0, Qimg);

  // ---- t14: out[b] = query[b] @ FT[b]^T + cv[b]  (512 blocks)
  gemm_img<<<dim3(16, 8, 4), 256, 0, stream>>>(Qimg, 4194304, FTimg, 2097152,
                                               cv, 1024, out, 2097152, 32, 1,
                                               0);
}

// Round 9
// 254.973 us; speedup vs baseline: 1.4205x; 1.1196x over previous
//
#include <hip/hip_runtime.h>

// ---------------------------------------------------------------------------
// MHA without softmax, fully reassociated:
//   out[b] = query[b] @ F[b] + cv[b]
//   F[b]   = 0.125 * WqM[b] @ Wo,  WqM[b] = Wq . blockdiag_h(M[b,h])
//   M[b,h] = Wk_h^T C[b] Wv_h + (Wk_h^T ksum) bv_h^T + bk_h (vsum^T Wv_h) + S bk_h bv_h^T
//   C[b]   = key[b]^T value[b]   (D := value^T key = C^T)
// Round 9: GEMM core untouched (at 937 TF-eq structural ceiling). Overhead
// fusion pass: colsum fused into KT/VT image build; Dimg+WkT+WoT one launch;
// FTimg+Qimg one launch; bqm folded into wqm. 19 -> 15 launches.
// ---------------------------------------------------------------------------

typedef __attribute__((ext_vector_type(8))) short short8;
typedef __attribute__((ext_vector_type(8))) unsigned short ushort8;
typedef __attribute__((ext_vector_type(4))) float f32x4;

__device__ __forceinline__ unsigned short f2bf(float x) {
  unsigned u = __builtin_bit_cast(unsigned, x);
  u += 0x7fffu + ((u >> 16) & 1u);  // RNE
  return (unsigned short)(u >> 16);
}
__device__ __forceinline__ float bf2f(unsigned short b) {
  unsigned u = ((unsigned)b) << 16;
  return __builtin_bit_cast(float, u);
}

__device__ __forceinline__ void gload16(const unsigned short* g, unsigned short* l) {
  __builtin_amdgcn_global_load_lds(
      (const __attribute__((address_space(1))) unsigned int*)g,
      (__attribute__((address_space(3))) unsigned int*)l, 16, 0, 0);
}

// ---------------------------------------------------------------------------
// build_img: stage one 128x32 tile of logical R[rows][K] into LDS (fp32),
// then write the split-bf16 blob: 8192 ushorts = hi[4][128][8] || lo[4][128][8]
//   transposed==0: R[r][k] = s[r][k]   (s row-major, 1024 cols)
//   transposed==1: R[r][k] = s[k][r]
//   nsum==2: element = s[x] + s[x + sumStride]  (split-K partial reduce)
// Leaves the fp32 tile in LDS for optional fused post-processing.
// ---------------------------------------------------------------------------
__device__ __forceinline__ void build_img(const float* __restrict__ s,
                                          int transposed, int nsum,
                                          long long sumStride, int rb, int kt,
                                          float (*tile)[36],
                                          unsigned short* __restrict__ blob) {
  const int t = threadIdx.x;
  if (!transposed) {
#pragma unroll
    for (int p = 0; p < 4; ++p) {
      const int idx = p * 1024 + t * 4;
      const int r = idx >> 5, k = idx & 31;
      const size_t off = (size_t)(rb * 128 + r) * 1024 + kt * 32 + k;
      float4 v = *(const float4*)&s[off];
      if (nsum == 2) {
        float4 u = *(const float4*)&s[off + sumStride];
        v.x += u.x; v.y += u.y; v.z += u.z; v.w += u.w;
      }
      *(float4*)&tile[r][k] = v;
    }
  } else {
#pragma unroll
    for (int p = 0; p < 4; ++p) {
      const int idx = p * 1024 + t * 4;
      const int k = idx >> 7, r = idx & 127;
      const size_t off = (size_t)(kt * 32 + k) * 1024 + rb * 128 + r;
      float4 v = *(const float4*)&s[off];
      tile[r + 0][k] = v.x;
      tile[r + 1][k] = v.y;
      tile[r + 2][k] = v.z;
      tile[r + 3][k] = v.w;
    }
  }
  __syncthreads();
  const int r = t >> 1, kh = (t & 1) * 16;
  ushort8 hi0, lo0, hi1, lo1;
#pragma unroll
  for (int j = 0; j < 8; ++j) {
    float x = tile[r][kh + j];
    unsigned short h = f2bf(x);
    hi0[j] = h;
    lo0[j] = f2bf(x - bf2f(h));
    float y = tile[r][kh + 8 + j];
    unsigned short g = f2bf(y);
    hi1[j] = g;
    lo1[j] = f2bf(y - bf2f(g));
  }
  const int k0sl = kh >> 3;  // 0 or 2
  *(ushort8*)&blob[k0sl * 1024 + r * 8] = hi0;
  *(ushort8*)&blob[(k0sl + 1) * 1024 + r * 8] = hi1;
  *(ushort8*)&blob[4096 + k0sl * 1024 + r * 8] = lo0;
  *(ushort8*)&blob[4096 + (k0sl + 1) * 1024 + r * 8] = lo1;
}

// ---------------------------------------------------------------------------
// kvimg: images of key^T (z0-3) and value^T (z4-7), NRB=8, NKT=64, PLUS fused
// per-(z,kt) column-sum partials (sum over the tile's 32 s per d) for the
// bias corrections. grid (8,64,8).
// ---------------------------------------------------------------------------
__global__ __launch_bounds__(256) void kvimg(const float* __restrict__ key,
                                             const float* __restrict__ value,
                                             unsigned short* __restrict__ KTimg,
                                             float* __restrict__ kvpart) {
  __shared__ __align__(16) float tile[128][36];
  const int rb = blockIdx.x, kt = blockIdx.y, z = blockIdx.z;
  const float* s = (z < 4) ? key + (size_t)z * 2097152
                           : value + (size_t)(z - 4) * 2097152;
  unsigned short* blob = KTimg + ((size_t)(z * 8 + rb) * 64 + kt) * 8192;
  build_img(s, 1, 1, 0, rb, kt, tile, blob);
  const int t = threadIdx.x, r = t >> 1, kh = (t & 1) * 16;
  float sum = 0.f;
#pragma unroll
  for (int j = 0; j < 16; ++j) sum += tile[r][kh + j];
  sum += __shfl_xor(sum, 1);
  if ((t & 1) == 0)
    kvpart[((size_t)z * 64 + kt) * 1024 + rb * 128 + r] = sum;
}

// ksum[b][d] = sum_kt kvpart[b][kt][d]; vsum from z=4+b
__global__ __launch_bounds__(256) void reduceks(const float* __restrict__ kvpart,
                                                float* __restrict__ ksum,
                                                float* __restrict__ vsum) {
  const int idx = blockIdx.x * 256 + threadIdx.x;  // 4096
  const int b = idx >> 10, d = idx & 1023;
  float sk = 0.f, sv = 0.f;
  for (int kt = 0; kt < 64; ++kt) {
    sk += kvpart[((size_t)b * 64 + kt) * 1024 + d];
    sv += kvpart[((size_t)(4 + b) * 64 + kt) * 1024 + d];
  }
  ksum[idx] = sk;
  vsum[idx] = sv;
}

// ---------------------------------------------------------------------------
// imgA: combo launch — Dimg (z0-3, row-major, nsum=dsplit) + WkT (z4) +
// WoT (z5) transposed images. grid (8,32,6).
// ---------------------------------------------------------------------------
__global__ __launch_bounds__(256) void imgA(
    const float* __restrict__ Dpart, int dsplit, const float* __restrict__ Wk,
    const float* __restrict__ Wo, unsigned short* __restrict__ Dimg,
    unsigned short* __restrict__ WkTimg, unsigned short* __restrict__ WoTimg) {
  __shared__ __align__(16) float tile[128][36];
  const int rb = blockIdx.x, kt = blockIdx.y, z = blockIdx.z;
  if (z < 4) {
    unsigned short* blob = Dimg + ((size_t)(z * 8 + rb) * 32 + kt) * 8192;
    build_img(Dpart + (size_t)z * 1048576, 0, dsplit, 4194304, rb, kt, tile,
              blob);
  } else if (z == 4) {
    unsigned short* blob = WkTimg + ((size_t)rb * 32 + kt) * 8192;
    build_img(Wk, 1, 1, 0, rb, kt, tile, blob);
  } else {
    unsigned short* blob = WoTimg + ((size_t)rb * 32 + kt) * 8192;
    build_img(Wo, 1, 1, 0, rb, kt, tile, blob);
  }
}

// ---------------------------------------------------------------------------
// imgB: combo launch — FTimg (z0-3, nsum=2, NRB=8) + Qimg (z4-7, NRB=16).
// grid (16,32,8); FT z's idle for rb>=8.
// ---------------------------------------------------------------------------
__global__ __launch_bounds__(256) void imgB(const float* __restrict__ FTpart,
                                            const float* __restrict__ query,
                                            unsigned short* __restrict__ FTimg,
                                            unsigned short* __restrict__ Qimg) {
  __shared__ __align__(16) float tile[128][36];
  const int rb = blockIdx.x, kt = blockIdx.y, z = blockIdx.z;
  if (z < 4) {
    if (rb >= 8) return;
    unsigned short* blob = FTimg + ((size_t)(z * 8 + rb) * 32 + kt) * 8192;
    build_img(FTpart + (size_t)z * 1048576, 0, 2, 4194304, rb, kt, tile, blob);
  } else {
    unsigned short* blob = Qimg + ((size_t)((z - 4) * 16 + rb) * 32 + kt) * 8192;
    build_img(query + (size_t)(z - 4) * 2097152, 0, 1, 0, rb, kt, tile, blob);
  }
}

// ---------------------------------------------------------------------------
// gemm_img: C[m][n] (+bias[n]) = sum_k A[m][k]*BT[n][k], split-bf16 3-MFMA.
// 128x128 tile, BK=32, 4 waves (2x2); LDS double-buffer via global_load_lds.
// Split-K: z = batch*nsplit + split.
// ---------------------------------------------------------------------------
__global__ __launch_bounds__(256) void gemm_img(
    const unsigned short* __restrict__ Aimg, long long sAb,
    const unsigned short* __restrict__ Bimg, long long sBb,
    const float* __restrict__ bias, long long sBiasB, float* __restrict__ C,
    long long sCb, int NKT, int nsplit, long long sSplit) {
  __shared__ __align__(16) unsigned short sAB[2][16384];
  const int tid = threadIdx.x, w = tid >> 6, l = tid & 63;

  // XCD-chunk swizzle (all grids have total % 8 == 0)
  const int gx = gridDim.x, gy = gridDim.y;
  int flat = blockIdx.x + gx * (blockIdx.y + gy * blockIdx.z);
  const int total = gx * gy * gridDim.z;
  flat = (flat & 7) * (total >> 3) + (flat >> 3);
  const int bx = flat % gx;
  const int rest = flat / gx;
  const int by = rest % gy, bz0 = rest / gy;
  const int batch = bz0 / nsplit, split = bz0 - batch * nsplit;
  const int NKT0 = NKT / nsplit, kt0 = split * NKT0;

  const unsigned short* Ab = Aimg + (size_t)batch * sAb + (size_t)bx * NKT * 8192;
  const unsigned short* Bb = Bimg + (size_t)batch * sBb + (size_t)by * NKT * 8192;

  f32x4 acc[4][4];
#pragma unroll
  for (int m = 0; m < 4; ++m)
#pragma unroll
    for (int n = 0; n < 4; ++n) acc[m][n] = f32x4{0.f, 0.f, 0.f, 0.f};

  const int wr = (w >> 1) * 64, wc = (w & 1) * 64, lr = l & 15, ksl = l >> 4;
  const int stg = w * 512 + l * 8;

#define STAGE(KT, BUF)                                                        \
  {                                                                           \
    const unsigned short* As_ = Ab + (size_t)(KT)*8192;                       \
    const unsigned short* Bs_ = Bb + (size_t)(KT)*8192;                       \
    _Pragma("unroll") for (int i = 0; i < 4; ++i)                             \
        gload16(As_ + i * 2048 + stg, &sAB[BUF][i * 2048 + w * 512]);         \
    _Pragma("unroll") for (int i = 0; i < 4; ++i)                             \
        gload16(Bs_ + i * 2048 + stg, &sAB[BUF][8192 + i * 2048 + w * 512]);  \
  }

  STAGE(kt0, 0);
  for (int kk = 0; kk < NKT0; ++kk) {
    __syncthreads();  // drains vmcnt(0): buf kk&1 ready; prev reads done
    if (kk + 1 < NKT0) STAGE(kt0 + kk + 1, (kk + 1) & 1);
    const unsigned short* sb = sAB[kk & 1];
    short8 ah[4], al[4], bh[4], bl[4];
#pragma unroll
    for (int m = 0; m < 4; ++m) {
      const int ro = ksl * 1024 + (wr + m * 16 + lr) * 8;
      ah[m] = *(const short8*)&sb[ro];
      al[m] = *(const short8*)&sb[4096 + ro];
    }
#pragma unroll
    for (int n = 0; n < 4; ++n) {
      const int ro = ksl * 1024 + (wc + n * 16 + lr) * 8;
      bh[n] = *(const short8*)&sb[8192 + ro];
      bl[n] = *(const short8*)&sb[12288 + ro];
    }
#pragma unroll
    for (int m = 0; m < 4; ++m)
#pragma unroll
      for (int n = 0; n < 4; ++n) {
        acc[m][n] = __builtin_amdgcn_mfma_f32_16x16x32_bf16(ah[m], bh[n], acc[m][n], 0, 0, 0);
        acc[m][n] = __builtin_amdgcn_mfma_f32_16x16x32_bf16(ah[m], bl[n], acc[m][n], 0, 0, 0);
        acc[m][n] = __builtin_amdgcn_mfma_f32_16x16x32_bf16(al[m], bh[n], acc[m][n], 0, 0, 0);
      }
  }
#undef STAGE

  float* Cb = C + (size_t)split * sSplit + (size_t)batch * sCb;
  const size_t m0 = (size_t)bx * 128, n0 = (size_t)by * 128;
#pragma unroll
  for (int n = 0; n < 4; ++n) {
    const size_t col = n0 + wc + n * 16 + lr;
    const float bval = bias ? bias[(size_t)batch * sBiasB + col] : 0.0f;
#pragma unroll
    for (int m = 0; m < 4; ++m) {
      const size_t rb = m0 + wr + m * 16 + ksl * 4;
#pragma unroll
      for (int r = 0; r < 4; ++r)
        Cb[(rb + r) * 1024 + col] = acc[m][n][r] + bval;
    }
  }
}

// ---------------------------------------------------------------------------
// u = Wk^T ksum, w = Wv^T vsum  (partials over 128-row chunks of the weights)
// ---------------------------------------------------------------------------
__global__ __launch_bounds__(256) void uvpart_kernel(
    const float* __restrict__ Wk, const float* __restrict__ Wv,
    const float* __restrict__ ksum, const float* __restrict__ vsum,
    float* __restrict__ part) {
  const int iseg = blockIdx.x;                          // 4
  const int dc = blockIdx.y & 7, kv = blockIdx.y >> 3;  // y: 16
  const int b = blockIdx.z;
  const int i = iseg * 256 + threadIdx.x;
  const float* W = kv ? Wv : Wk;
  const float* sv = (kv ? vsum : ksum) + b * 1024 + dc * 128;
  float s = 0.f;
  for (int dd = 0; dd < 128; ++dd)
    s += W[(size_t)(dc * 128 + dd) * 1024 + i] * sv[dd];
  part[(((size_t)kv * 4 + b) * 8 + dc) * 1024 + i] = s;
}

__global__ __launch_bounds__(256) void reduceuv(const float* __restrict__ part,
                                                float* __restrict__ uv) {
  const int idx = blockIdx.x * 256 + threadIdx.x;  // 8192
  const int kb = idx >> 10, i = idx & 1023;
  float s = 0.f;
#pragma unroll
  for (int dc = 0; dc < 8; ++dc) s += part[((size_t)kb * 8 + dc) * 1024 + i];
  uv[idx] = s;
}

// ---------------------------------------------------------------------------
// mstep: Mpart[chunk][bh][r][c] = sum_{e in chunk(256)} T[b][h64+r][e]*Wv[e][h64+c]
// T given as 2 split-K partials: T[x] + T[x + tSplit]
// ---------------------------------------------------------------------------
__global__ __launch_bounds__(256) void mstep(const float* __restrict__ T,
                                             long long tSplit,
                                             const float* __restrict__ Wv,
                                             float* __restrict__ Mpart) {
  const int chunk = blockIdx.x;  // 0..3
  const int bh = blockIdx.y;
  const int b = bh >> 4, h = bh & 15;
  __shared__ float Ts[64][68];
  __shared__ float Ws[64][68];
  const int tid = threadIdx.x;
  const int r0 = tid >> 4, c0 = (tid & 15) * 4;
  float acc[4][4] = {};
  const int e0 = chunk * 256;
  for (int slab = 0; slab < 4; ++slab) {
    __syncthreads();
#pragma unroll
    for (int t = 0; t < 4; ++t) {
      const int task = tid + t * 256;
      const int si = task >> 4, c4 = (task & 15) * 4;
      const size_t toff = (size_t)b * 1048576 + (size_t)(h * 64 + si) * 1024 +
                          e0 + slab * 64 + c4;
      float4 tv = *(const float4*)&T[toff];
      float4 tu = *(const float4*)&T[toff + tSplit];
      tv.x += tu.x; tv.y += tu.y; tv.z += tu.z; tv.w += tu.w;
      *(float4*)&Ts[si][c4] = tv;
      *(float4*)&Ws[si][c4] =
          *(const float4*)&Wv[(size_t)(e0 + slab * 64 + si) * 1024 + h * 64 + c4];
    }
    __syncthreads();
    for (int e = 0; e < 64; ++e) {
      const float4 wv = *(const float4*)&Ws[e][c0];
#pragma unroll
      for (int i = 0; i < 4; ++i) {
        const float tt = Ts[r0 + 16 * i][e];
        acc[i][0] += tt * wv.x;
        acc[i][1] += tt * wv.y;
        acc[i][2] += tt * wv.z;
        acc[i][3] += tt * wv.w;
      }
    }
  }
  float* outp = Mpart + ((size_t)chunk * 64 + bh) * 4096;
#pragma unroll
  for (int i = 0; i < 4; ++i)
    *(float4*)&outp[(r0 + 16 * i) * 64 + c0] = *(float4*)&acc[i][0];
}

// M = sum(Mpart) + rank-1 bias corrections
__global__ __launch_bounds__(256) void reduce4corr(
    const float* __restrict__ Mpart, const float* __restrict__ uv,
    const float* __restrict__ bk, const float* __restrict__ bv,
    float* __restrict__ M) {
  const int idx = blockIdx.x * 256 + threadIdx.x;  // 262144
  const int bh = idx >> 12, b = bh >> 4, h = bh & 15;
  const int rc = idx & 4095;
  const int r = h * 64 + (rc >> 6), c = h * 64 + (rc & 63);
  float s = Mpart[idx] + Mpart[262144 + idx] + Mpart[524288 + idx] +
            Mpart[786432 + idx];
  s += uv[b * 1024 + r] * bv[c] + bk[r] * uv[4096 + b * 1024 + c] +
       2048.0f * bk[r] * bv[c];
  M[idx] = s;
}

// ---------------------------------------------------------------------------
// wqm_kernel: WqM[b][d][h*64+c] = 0.125 * sum_r Wq[d][h*64+r] * M[b,h][r][c],
// written DIRECTLY as split-bf16 image. dseg==0 blocks also compute
// bqM[b][h*64+c] = sum_r bq[h*64+r]*M[b,h][r][c] (M already in LDS).
// ---------------------------------------------------------------------------
__global__ __launch_bounds__(256) void wqm_kernel(const float* __restrict__ M,
                                                  const float* __restrict__ Wq,
                                                  const float* __restrict__ bq,
                                                  unsigned short* __restrict__ img,
                                                  float* __restrict__ bqM) {
  const int dseg = blockIdx.x, h = blockIdx.y, b = blockIdx.z;
  __shared__ __align__(16) float WqS[128][68];
  __shared__ __align__(16) float Ms[64][68];
  const int t = threadIdx.x;
#pragma unroll
  for (int it = 0; it < 8; ++it) {
    const int task = t + it * 256;
    const int row = task >> 4, c4 = (task & 15) * 4;
    *(float4*)&WqS[row][c4] =
        *(const float4*)&Wq[(size_t)(dseg * 128 + row) * 1024 + h * 64 + c4];
  }
#pragma unroll
  for (int it = 0; it < 4; ++it) {
    const int task = t + it * 256;
    const int row = task >> 4, c4 = (task & 15) * 4;
    *(float4*)&Ms[row][c4] =
        *(const float4*)&M[((size_t)(b * 16 + h)) * 4096 + row * 64 + c4];
  }
  __syncthreads();

  const int c0 = (t & 7) * 8;
  const int d0 = t >> 3;
  float4 a0[4], a1[4];
#pragma unroll
  for (int i = 0; i < 4; ++i) {
    a0[i] = float4{0.f, 0.f, 0.f, 0.f};
    a1[i] = float4{0.f, 0.f, 0.f, 0.f};
  }
  for (int r = 0; r < 64; ++r) {
    const float4 m0 = *(const float4*)&Ms[r][c0];
    const float4 m1 = *(const float4*)&Ms[r][c0 + 4];
#pragma unroll
    for (int i = 0; i < 4; ++i) {
      const float w = WqS[d0 + 32 * i][r];
      a0[i].x += w * m0.x; a0[i].y += w * m0.y; a0[i].z += w * m0.z; a0[i].w += w * m0.w;
      a1[i].x += w * m1.x; a1[i].y += w * m1.y; a1[i].z += w * m1.z; a1[i].w += w * m1.w;
    }
  }
  const int kt = h * 2 + (c0 >> 5);
  const int ksl = (c0 >> 3) & 3;
  unsigned short* blob = img + ((size_t)((b * 8 + dseg) * 32 + kt)) * 8192;
#pragma unroll
  for (int i = 0; i < 4; ++i) {
    const int r = d0 + 32 * i;
    float v[8] = {a0[i].x * 0.125f, a0[i].y * 0.125f, a0[i].z * 0.125f,
                  a0[i].w * 0.125f, a1[i].x * 0.125f, a1[i].y * 0.125f,
                  a1[i].z * 0.125f, a1[i].w * 0.125f};
    ushort8 hi, lo;
#pragma unroll
    for (int j = 0; j < 8; ++j) {
      unsigned short hh = f2bf(v[j]);
      hi[j] = hh;
      lo[j] = f2bf(v[j] - bf2f(hh));
    }
    *(ushort8*)&blob[ksl * 1024 + r * 8] = hi;
    *(ushort8*)&blob[4096 + ksl * 1024 + r * 8] = lo;
  }

  if (dseg == 0 && t < 64) {
    float s = 0.f;
#pragma unroll
    for (int r = 0; r < 64; ++r) s += bq[h * 64 + r] * Ms[r][t];
    bqM[(size_t)b * 1024 + h * 64 + t] = s;
  }
}

// cvpart[(b*8+ks)*1024+j] = sum_{k in ks-chunk(128)} bqM[b][k]*Wo[k][j]
__global__ __launch_bounds__(256) void cvpart_kernel(
    const float* __restrict__ bqM, const float* __restrict__ Wo,
    float* __restrict__ cvpart) {
  const int jseg = blockIdx.x, ks = blockIdx.y;
  const int j = jseg * 256 + threadIdx.x;
  float s0 = 0.f, s1 = 0.f, s2 = 0.f, s3 = 0.f;
  for (int k = 0; k < 128; ++k) {
    const float wv = Wo[(size_t)(ks * 128 + k) * 1024 + j];
    s0 += bqM[ks * 128 + k] * wv;
    s1 += bqM[1024 + ks * 128 + k] * wv;
    s2 += bqM[2048 + ks * 128 + k] * wv;
    s3 += bqM[3072 + ks * 128 + k] * wv;
  }
  cvpart[((size_t)0 * 8 + ks) * 1024 + j] = s0;
  cvpart[((size_t)1 * 8 + ks) * 1024 + j] = s1;
  cvpart[((size_t)2 * 8 + ks) * 1024 + j] = s2;
  cvpart[((size_t)3 * 8 + ks) * 1024 + j] = s3;
}

// cv[b][j] = bo[j] + 0.125 * sum_ks cvpart[(b*8+ks)*1024+j]
__global__ __launch_bounds__(256) void cvred(const float* __restrict__ cvpart,
                                             const float* __restrict__ bo,
                                             float* __restrict__ cv) {
  const int idx = blockIdx.x * 256 + threadIdx.x;  // 4096
  const int b = idx >> 10, j = idx & 1023;
  float s = 0.f;
#pragma unroll
  for (int ks = 0; ks < 8; ++ks) s += cvpart[((size_t)b * 8 + ks) * 1024 + j];
  cv[idx] = s * 0.125f + bo[j];
}

extern "C" void kernel_launch(void* const* d_in, const int* in_sizes, int n_in,
                              void* d_out, int out_size, void* d_ws,
                              size_t ws_size, hipStream_t stream) {
  const float* query = (const float*)d_in[0];
  const float* key = (const float*)d_in[1];
  const float* value = (const float*)d_in[2];
  const float* Wq = (const float*)d_in[3];
  const float* bq = (const float*)d_in[4];
  const float* Wk = (const float*)d_in[5];
  const float* bk = (const float*)d_in[6];
  const float* Wv = (const float*)d_in[7];
  const float* bv = (const float*)d_in[8];
  const float* Wo = (const float*)d_in[9];
  const float* bo = (const float*)d_in[10];
  float* out = (float*)d_out;
  float* ws = (float*)d_ws;

  const bool big = ws_size >= (size_t)101019648;
  const int dsplit = big ? 2 : 1;

  // ---- layout (float offsets). Timeline-audited.
  // [0,64MB)  KT(z0-3)+VT(z4-7) images -> after t5: WqMimg [0,16) ;
  //           WkTimg [16,20) ; WoTimg [20,24) ; Mpart [24,28) ; Msum [28,29)
  //           -> after FT gemm: Qimg [0,32)
  // [32,64MB) Tpart -> FTpart
  // [64,*)    kvpart/uvpart (early, 2MB) -> Dpart (big [64,96) | small
  //           [64,80)) -> FTimg [64,80)
  // smalls:   big @96MB | small @80MB
  unsigned short* KTimg = (unsigned short*)ws;
  unsigned short* VTimg = (unsigned short*)ws + 16777216;     // 32MB
  float* kvpart = ws + 16777216;                              // 64MB (early)
  float* Dpart = ws + 16777216;                               // 64MB
  unsigned short* Dimg = (unsigned short*)ws;                 // 0MB
  unsigned short* WkTimg = (unsigned short*)(ws + 4194304);   // 16MB
  unsigned short* WoTimg = WkTimg + 2097152;                  // 20MB
  float* Mpart = ws + 6291456;                                // 24MB
  float* Msum = ws + 7340032;                                 // 28MB
  float* Tpart = ws + 8388608;                                // 32MB (2x16MB)
  unsigned short* WqMimg = (unsigned short*)ws;               // 0MB (Dimg dead)
  float* FTpart = ws + 8388608;                               // 32MB (2x16MB)
  unsigned short* FTimg = (unsigned short*)(ws + 16777216);   // 64MB
  unsigned short* Qimg = (unsigned short*)ws;                 // 0MB (32MB wide)
  float* smalls = ws + (big ? 25165824 : 20971520);           // 96MB | 80MB
  float* ksum = smalls;            // 4096
  float* vsum = smalls + 4096;     // 4096
  float* uv = smalls + 8192;       // 8192
  float* bqM = smalls + 16384;     // 4096
  float* cvpartb = smalls + 20480; // 32768
  float* cv = smalls + 53248;      // 4096

  // ---- t1: key^T/value^T images + fused column-sum partials
  kvimg<<<dim3(8, 64, 8), 256, 0, stream>>>(key, value, KTimg, kvpart);
  reduceks<<<16, 256, 0, stream>>>(kvpart, ksum, vsum);
  uvpart_kernel<<<dim3(4, 16, 4), 256, 0, stream>>>(Wk, Wv, ksum, vsum, kvpart);
  reduceuv<<<32, 256, 0, stream>>>(kvpart, uv);

  // ---- t2: D[b] = value^T key (= C^T), K=2048
  gemm_img<<<dim3(8, 8, 4 * dsplit), 256, 0, stream>>>(
      VTimg, 4194304, KTimg, 4194304, (const float*)nullptr, 0, Dpart, 1048576,
      64, dsplit, 4194304);

  // ---- t3: Dimg + WkT + WoT images in one launch (KT region dead)
  imgA<<<dim3(8, 32, 6), 256, 0, stream>>>(Dpart, dsplit, Wk, Wo, Dimg,
                                           WkTimg, WoTimg);

  // ---- t5: T[b] = WkT . D^T (= Wk^T C), split-K x2 -> 512 blocks (VT dead)
  gemm_img<<<dim3(8, 8, 8), 256, 0, stream>>>(WkTimg, 0, Dimg, 2097152,
                                              (const float*)nullptr, 0, Tpart,
                                              1048576, 32, 2, 4194304);

  // ---- t6/t7: M[b,h] = T_h . Wv_h + rank-1 bias corrections (fp32 exact)
  mstep<<<dim3(4, 64), 256, 0, stream>>>(Tpart, 4194304, Wv, Mpart);
  reduce4corr<<<1024, 256, 0, stream>>>(Mpart, uv, bk, bv, Msum);

  // ---- t8: WqM image directly (Dimg dead after t5) + fused bqM
  wqm_kernel<<<dim3(8, 16, 4), 256, 0, stream>>>(Msum, Wq, bq, WqMimg, bqM);
  cvpart_kernel<<<dim3(4, 8), 256, 0, stream>>>(bqM, Wo, cvpartb);
  cvred<<<16, 256, 0, stream>>>(cvpartb, bo, cv);

  // ---- t11: FT[b] = (WqM[b] @ Wo)^T, split-K x2 (Tpart dead)
  gemm_img<<<dim3(8, 8, 8), 256, 0, stream>>>(WoTimg, 0, WqMimg, 2097152,
                                              (const float*)nullptr, 0, FTpart,
                                              1048576, 32, 2, 4194304);

  // ---- t12: FTimg + Qimg in one launch (WqMimg/WkT/WoT/Mpart dead)
  imgB<<<dim3(16, 32, 8), 256, 0, stream>>>(FTpart, query, FTimg, Qimg);

  // ---- t14: out[b] = query[b] @ FT[b]^T + cv[b]
  gemm_img<<<dim3(16, 8, 4), 256, 0, stream>>>(Qimg, 4194304, FTimg, 2097152,
                                               cv, 1024, out, 2097152, 32, 1,
                                               0);
}